// Round 9
// baseline (789.924 us; speedup 1.0000x reference)
//
#include <hip/hip_runtime.h>
#include <stdint.h>

typedef unsigned short U16;
typedef float f32x4 __attribute__((ext_vector_type(4)));
typedef __bf16 bf16x8 __attribute__((ext_vector_type(8)));

static __device__ __forceinline__ U16 f2bf(float x) {
  union { float f; unsigned u; } v; v.f = x;
  unsigned r = v.u + 0x7FFFu + ((v.u >> 16) & 1u);
  return (U16)(r >> 16);
}
static __device__ __forceinline__ float bf2f(U16 h) {
  union { unsigned u; float f; } v; v.u = ((unsigned)h) << 16;
  return v.f;
}

static __device__ __forceinline__ void gload_lds16(const void* g, void* l) {
  __builtin_amdgcn_global_load_lds(
      (const __attribute__((address_space(1))) void*)g,
      (__attribute__((address_space(3))) void*)l, 16, 0, 0);
}

// ---------------- hidden (fp32) -> bf16 -------------------------------------
__global__ __launch_bounds__(256) void k_convert(const float* __restrict__ src,
                                                 U16* __restrict__ dst, long n) {
  long base = ((long)blockIdx.x * 256 + threadIdx.x) * 8;
  if (base >= n) return;
  const float4* s = (const float4*)(src + base);
  float4 a = s[0], b = s[1];
  U16 o[8] = { f2bf(a.x), f2bf(a.y), f2bf(a.z), f2bf(a.w),
               f2bf(b.x), f2bf(b.y), f2bf(b.z), f2bf(b.w) };
  *(uint4*)(dst + base) = *(const uint4*)o;
}

// ---------------- W[K][N] (fp32) -> Wt[N][K] bf16 ----------------------------
__global__ __launch_bounds__(256) void k_transpose(const float* __restrict__ src,
                                                   U16* __restrict__ dst,
                                                   int K, int N) {
  __shared__ U16 tile[32][33];
  int n0 = blockIdx.x * 32, k0 = blockIdx.y * 32;
  int tx = threadIdx.x & 31, ty = threadIdx.x >> 5;
#pragma unroll
  for (int r = 0; r < 4; ++r) {
    int k = k0 + ty + r * 8;
    tile[ty + r * 8][tx] = f2bf(src[(long)k * N + n0 + tx]);
  }
  __syncthreads();
#pragma unroll
  for (int r = 0; r < 4; ++r) {
    int n = n0 + ty + r * 8;
    dst[(long)n * K + k0 + tx] = tile[tx][ty + r * 8];
  }
}

// ---- V section of QKV -> VT tiled [bk][sTile=64][d=256][s32=32] bf16 -------
__global__ __launch_bounds__(256) void k_vtrans(const U16* __restrict__ QKV,
                                                U16* __restrict__ VT) {
  __shared__ U16 tile[32][33];
  int s0 = blockIdx.x * 32, d0 = blockIdx.y * 32, bk = blockIdx.z;
  int b = bk >> 3, kvh = bk & 7;
  int tx = threadIdx.x & 31, ty = threadIdx.x >> 5;
  const U16* src = QKV + (long)(b * 2048) * 8192 + 6144 + kvh * 256;
#pragma unroll
  for (int r = 0; r < 4; ++r) {
    int s = s0 + ty + r * 8;
    tile[ty + r * 8][tx] = src[(long)s * 8192 + d0 + tx];
  }
  __syncthreads();
  long tbase = ((long)bk * 64 + (s0 >> 5)) * 8192;   // 256*32 per tile
#pragma unroll
  for (int r = 0; r < 4; ++r) {
    int d = d0 + ty + r * 8;
    VT[tbase + d * 32 + tx] = tile[tx][ty + r * 8];
  }
}

// ---------------- RoPE tables (fp32) ----------------------------------------
__global__ __launch_bounds__(256) void k_rope_tables(float* __restrict__ cosT,
                                                     float* __restrict__ sinT) {
  int i = blockIdx.x * 256 + threadIdx.x;
  int s = i >> 7, d = i & 127;
  float freq = expf(-9.210340371976184f * (float)d / 128.0f);
  float ang = (float)s * freq;
  cosT[i] = cosf(ang);
  sinT[i] = sinf(ang);
}

// ---------------- RoPE in place on q,k sections of QKV ----------------------
__global__ __launch_bounds__(256) void k_rope(U16* __restrict__ qkv,
                                              const float* __restrict__ cosT,
                                              const float* __restrict__ sinT) {
  int i = blockIdx.x * 256 + threadIdx.x;
  int d = i & 127;
  int hh = (i >> 7) % 24;
  int row = i / 3072;
  int s = row & 2047;
  int col = (hh < 16) ? hh * 256 + d : 4096 + (hh - 16) * 256 + d;
  long base = (long)row * 8192 + col;
  float c = cosT[s * 128 + d], sn = sinT[s * 128 + d];
  float x1 = bf2f(qkv[base]), x2 = bf2f(qkv[base + 128]);
  qkv[base]       = f2bf(x1 * c - x2 * sn);
  qkv[base + 128] = f2bf(x2 * c + x1 * sn);
}

// ---------------- GEMM v3: 256x256, 8 waves, 3-deep pipeline, ---------------
// FRAGMENT-LINEAR LDS layout. Granule G = f*64 + l15*4 + l4 (f = 16-row
// fragment id) holds row f*16+l15, bf16 cols l4*8..+7. Staging writes are
// lane-linear (gload_lds dest = base + lane*16); the SOURCE address encodes
// the permutation. Every ds_read_b128 reads 64 distinct consecutive granules
// -> zero bank conflict by construction; frag reads are base + m*1024.
template <int F32OUT>
__global__ __launch_bounds__(512, 2) void k_gemm2(const U16* __restrict__ A,
                                                  const U16* __restrict__ Bt,
                                                  void* __restrict__ Cv,
                                                  int M, int N, int K) {
  __shared__ __align__(16) U16 Ab[3][256 * 32];
  __shared__ __align__(16) U16 Bb[3][256 * 32];
  int nwg = gridDim.x * gridDim.y;
  int flat = blockIdx.y * gridDim.x + blockIdx.x;
  int cpx = nwg >> 3;
  int swz = (flat & 7) * cpx + (flat >> 3);
  int bx = swz % gridDim.x, by = swz / gridDim.x;
  int t = threadIdx.x, lane = t & 63, w = t >> 6;
  int m0 = by * 256, n0 = bx * 256;
  int wm = w >> 2, wn = w & 3;
  int l15 = lane & 15, l4 = lane >> 4;

  f32x4 acc[8][4] = {};

  // staging source: issue i, wave w stages fragment f = i*8 + w;
  // lane covers row f*16 + (lane>>2), bf16 col (lane&3)*8.
  int sr = lane >> 2, sc = (lane & 3) * 8;
  const U16* gA0 = A + (long)(m0 + w * 16 + sr) * K + sc;
  const U16* gA1 = A + (long)(m0 + 128 + w * 16 + sr) * K + sc;
  const U16* gB0 = Bt + (long)(n0 + w * 16 + sr) * K + sc;
  const U16* gB1 = Bt + (long)(n0 + 128 + w * 16 + sr) * K + sc;

  auto stage = [&](int buf, int kt) {
    long k0 = (long)kt * 32;
    gload_lds16(gA0 + k0, (char*)&Ab[buf][0] + w * 1024);
    gload_lds16(gA1 + k0, (char*)&Ab[buf][0] + 8192 + w * 1024);
    gload_lds16(gB0 + k0, (char*)&Bb[buf][0] + w * 1024);
    gload_lds16(gB1 + k0, (char*)&Bb[buf][0] + 8192 + w * 1024);
  };

  auto compute = [&](int buf) {
    const char* Ac = (const char*)&Ab[buf][0] + (l15 * 4 + l4) * 16;
    const char* Bc = (const char*)&Bb[buf][0] + (l15 * 4 + l4) * 16;
    bf16x8 af[8], bb[4];
#pragma unroll
    for (int m = 0; m < 8; ++m)
      af[m] = *(const bf16x8*)(Ac + (wm * 8 + m) * 1024);
#pragma unroll
    for (int n = 0; n < 4; ++n)
      bb[n] = *(const bf16x8*)(Bc + (wn * 4 + n) * 1024);
    __builtin_amdgcn_s_setprio(1);
#pragma unroll
    for (int m = 0; m < 8; ++m)
#pragma unroll
      for (int n = 0; n < 4; ++n)
        acc[m][n] = __builtin_amdgcn_mfma_f32_16x16x32_bf16(af[m], bb[n], acc[m][n], 0, 0, 0);
    __builtin_amdgcn_s_setprio(0);
  };

  int T = K >> 5;
  stage(0, 0);
  stage(1, 1);
  asm volatile("s_waitcnt vmcnt(4)" ::: "memory");
  __builtin_amdgcn_sched_barrier(0);
  __builtin_amdgcn_s_barrier();
  __builtin_amdgcn_sched_barrier(0);

  int cur = 0, stb = 2;
  for (int kt = 0; kt < T - 2; ++kt) {
    stage(stb, kt + 2);
    compute(cur);
    asm volatile("s_waitcnt vmcnt(4)" ::: "memory");
    __builtin_amdgcn_sched_barrier(0);
    __builtin_amdgcn_s_barrier();
    __builtin_amdgcn_sched_barrier(0);
    cur = (cur + 1 == 3) ? 0 : cur + 1;
    stb = (stb + 1 == 3) ? 0 : stb + 1;
  }
  compute(cur);                                  // tile T-2
  asm volatile("s_waitcnt vmcnt(0)" ::: "memory");
  __builtin_amdgcn_sched_barrier(0);
  __builtin_amdgcn_s_barrier();
  __builtin_amdgcn_sched_barrier(0);
  cur = (cur + 1 == 3) ? 0 : cur + 1;
  compute(cur);                                  // tile T-1

  // epilogue
#pragma unroll
  for (int m = 0; m < 8; ++m)
#pragma unroll
    for (int jj = 0; jj < 4; ++jj) {
      int row = m0 + wm * 128 + m * 16 + l4 * 4 + jj;
      if (F32OUT) {
        float* cp = (float*)Cv + (long)row * N + n0 + wn * 64 + l15;
#pragma unroll
        for (int n = 0; n < 4; ++n) cp[n * 16] = acc[m][n][jj];
      } else {
        U16* cp = (U16*)Cv + (long)row * N + n0 + wn * 64 + l15;
#pragma unroll
        for (int n = 0; n < 4; ++n) cp[n * 16] = f2bf(acc[m][n][jj]);
      }
    }
}

// ---------------- banded GQA attention (v5, unchanged) ----------------------
__global__ __launch_bounds__(256) void k_attn(const U16* __restrict__ QKV,
                                              const U16* __restrict__ VT,
                                              U16* __restrict__ O) {
  __shared__ __align__(16) U16 Ks[2][32 * 256];
  __shared__ __align__(16) U16 Vs[2][256 * 32];
  __shared__ __align__(16) U16 Plds[4][16 * 40];
  int t = threadIdx.x, lane = t & 63, w = t >> 6;
  int flat = blockIdx.x + 32 * (blockIdx.y + 16 * blockIdx.z);
  int l = (flat & 7) * 128 + (flat >> 3);
  int qb = l & 31, h = (l >> 5) & 15, b = l >> 9;
  int s0 = qb * 64;
  int kvh = h >> 1;
  long rowOff = (long)b * 2048 * 8192;
  const U16* Qb = QKV + rowOff + h * 256;
  const U16* Kb = QKV + rowOff + 4096 + kvh * 256;
  const U16* VTb = VT + (long)(b * 8 + kvh) * 64 * 8192;

  int l15 = lane & 15, l4 = lane >> 4;

  bf16x8 qf[8];
  {
    const U16* qp = Qb + (long)(s0 + w * 16 + l15) * 8192 + l4 * 8;
#pragma unroll
    for (int kc = 0; kc < 8; ++kc) qf[kc] = *(const bf16x8*)(qp + kc * 32);
  }
  asm volatile("s_waitcnt vmcnt(0)" ::: "memory");

  f32x4 acc[16] = {};
  float mrun = -1e30f, lrun = 0.0f;
  int qpos = s0 + w * 16 + l15;

  int kstart = s0 - 1024; if (kstart < 0) kstart = 0;
  int kend = s0 + 64 + 1024; if (kend > 2048) kend = 2048;

  auto stage = [&](int buf, int k0) {
#pragma unroll
    for (int i = 0; i < 4; ++i) {
      int g = i * 256 + t;
      int row = g >> 5, c = g & 31;
      int cs = c ^ (row & 7);
      gload_lds16(Kb + (long)(k0 + row) * 8192 + cs * 8,
                  (char*)&Ks[buf][0] + i * 4096 + w * 1024);
    }
    const U16* vtile = VTb + (long)(k0 >> 5) * 8192;
#pragma unroll
    for (int i = 0; i < 4; ++i) {
      int g = i * 256 + t;
      int d = g >> 2, c = g & 3;
      int cs = c ^ ((d >> 1) & 3);
      gload_lds16(vtile + d * 32 + cs * 8,
                  (char*)&Vs[buf][0] + i * 4096 + w * 1024);
    }
  };

  auto compute = [&](int buf, int k0) {
    f32x4 sAcc[2] = {};
    __builtin_amdgcn_s_setprio(1);
#pragma unroll
    for (int kc = 0; kc < 8; ++kc) {
      int c0 = ((kc * 4 + l4) ^ (l15 & 7)) * 8;
      bf16x8 a0 = *(const bf16x8*)&Ks[buf][l15 * 256 + c0];
      bf16x8 a1 = *(const bf16x8*)&Ks[buf][(16 + l15) * 256 + c0];
      sAcc[0] = __builtin_amdgcn_mfma_f32_16x16x32_bf16(a0, qf[kc], sAcc[0], 0, 0, 0);
      sAcc[1] = __builtin_amdgcn_mfma_f32_16x16x32_bf16(a1, qf[kc], sAcc[1], 0, 0, 0);
    }
    __builtin_amdgcn_s_setprio(0);
    float sv[8];
#pragma unroll
    for (int mp = 0; mp < 2; ++mp)
#pragma unroll
      for (int jj = 0; jj < 4; ++jj) {
        int key = k0 + mp * 16 + l4 * 4 + jj;
        float x = sAcc[mp][jj] * 0.00125f;
        float ex = __expf(2.0f * x);
        float z = 50.0f * (ex - 1.0f) / (ex + 1.0f);
        int dd = qpos - key;
        if (dd < -1024 || dd > 1024) z = -3e38f;
        sv[mp * 4 + jj] = z;
      }
    float tmax = sv[0];
#pragma unroll
    for (int i = 1; i < 8; ++i) tmax = fmaxf(tmax, sv[i]);
    tmax = fmaxf(tmax, __shfl_xor(tmax, 16));
    tmax = fmaxf(tmax, __shfl_xor(tmax, 32));
    bool skipall = __all((tmax <= mrun + 8.0f) ? 1 : 0) != 0;
    float mnew = skipall ? mrun : fmaxf(mrun, tmax);
    float pex[8];
    float psum = 0.0f;
#pragma unroll
    for (int i = 0; i < 8; ++i) { pex[i] = __expf(sv[i] - mnew); psum += pex[i]; }
    psum += __shfl_xor(psum, 16);
    psum += __shfl_xor(psum, 32);
    if (skipall) {
      lrun += psum;
    } else {
      float esc = __expf(mrun - mnew);
      f32x4 ev;
#pragma unroll
      for (int jj = 0; jj < 4; ++jj) ev[jj] = __shfl(esc, l4 * 4 + jj);
#pragma unroll
      for (int n = 0; n < 16; ++n) acc[n] *= ev;
      lrun = lrun * esc + psum;
      mrun = mnew;
    }
#pragma unroll
    for (int mp = 0; mp < 2; ++mp)
#pragma unroll
      for (int j2 = 0; j2 < 2; ++j2) {
        unsigned lo = f2bf(pex[mp * 4 + j2 * 2]);
        unsigned hi = f2bf(pex[mp * 4 + j2 * 2 + 1]);
        *(unsigned*)&Plds[w][l15 * 40 + mp * 16 + l4 * 4 + j2 * 2] = lo | (hi << 16);
      }
    asm volatile("s_waitcnt lgkmcnt(0)" ::: "memory");
    __builtin_amdgcn_sched_barrier(0);
    bf16x8 pa = *(const bf16x8*)&Plds[w][l15 * 40 + l4 * 8];
    __builtin_amdgcn_s_setprio(1);
#pragma unroll
    for (int n = 0; n < 16; ++n) {
      int d = n * 16 + l15;
      int c = (l4 ^ ((d >> 1) & 3)) * 8;
      bf16x8 vb = *(const bf16x8*)&Vs[buf][d * 32 + c];
      acc[n] = __builtin_amdgcn_mfma_f32_16x16x32_bf16(pa, vb, acc[n], 0, 0, 0);
    }
    __builtin_amdgcn_s_setprio(0);
  };

  int cur = 0;
  stage(0, kstart);
  for (int k0 = kstart; k0 < kend - 32; k0 += 32) {
    stage(cur ^ 1, k0 + 32);
    asm volatile("s_waitcnt vmcnt(8)" ::: "memory");
    __builtin_amdgcn_s_barrier();
    __builtin_amdgcn_sched_barrier(0);
    compute(cur, k0);
    __builtin_amdgcn_s_barrier();
    cur ^= 1;
  }
  asm volatile("s_waitcnt vmcnt(0)" ::: "memory");
  __builtin_amdgcn_s_barrier();
  __builtin_amdgcn_sched_barrier(0);
  compute(cur, kend - 32);

  f32x4 linv;
#pragma unroll
  for (int jj = 0; jj < 4; ++jj) linv[jj] = 1.0f / __shfl(lrun, l4 * 4 + jj);
#pragma unroll
  for (int jj = 0; jj < 4; ++jj) {
    int row = s0 + w * 16 + l4 * 4 + jj;
    U16* op = O + ((long)b * 2048 + row) * 4096 + h * 256 + l15;
#pragma unroll
    for (int n = 0; n < 16; ++n) op[n * 16] = f2bf(acc[n][jj] * linv[jj]);
  }
}

// ----------------------------------------------------------------------------
extern "C" void kernel_launch(void* const* d_in, const int* in_sizes, int n_in,
                              void* d_out, int out_size, void* d_ws, size_t ws_size,
                              hipStream_t stream) {
  if (n_in < 5) return;
  const float* hid = (const float*)d_in[0];
  const float* Wq  = (const float*)d_in[1];
  const float* Wk  = (const float*)d_in[2];
  const float* Wv  = (const float*)d_in[3];
  const float* Wo  = (const float*)d_in[4];

  char* ws = (char*)d_ws;
  size_t off = 0;
  auto alloc = [&](size_t bytes) {
    char* p = ws + off;
    off += (bytes + 255) & ~(size_t)255;
    return p;
  };
  float* cosT = (float*)alloc((size_t)2048 * 128 * 4);
  float* sinT = (float*)alloc((size_t)2048 * 128 * 4);
  U16*   Xb   = (U16*)alloc((size_t)4096 * 3584 * 2);   // reused: VT, then Wot
  U16*   Wt   = (U16*)alloc((size_t)8192 * 3584 * 2);   // reused: AttO
  U16*   QKV  = (U16*)alloc((size_t)4096 * 8192 * 2);
  if (off > ws_size) return;
  U16* VT   = Xb;                 // 16*64*8192*2 B = 16.8 MB < |Xb|
  U16* Wot  = Xb;                 // written after attn (VT dead by then)
  U16* AttO = Wt;

  k_convert<<<7168, 256, 0, stream>>>(hid, Xb, (long)4096 * 3584);
  k_transpose<<<dim3(128, 112), 256, 0, stream>>>(Wq, Wt, 3584, 4096);
  k_transpose<<<dim3(64, 112), 256, 0, stream>>>(Wk, Wt + (size_t)4096 * 3584, 3584, 2048);
  k_transpose<<<dim3(64, 112), 256, 0, stream>>>(Wv, Wt + (size_t)6144 * 3584, 3584, 2048);
  k_rope_tables<<<1024, 256, 0, stream>>>(cosT, sinT);
  k_gemm2<0><<<dim3(32, 16), 512, 0, stream>>>(Xb, Wt, QKV, 4096, 8192, 3584);
  k_vtrans<<<dim3(64, 8, 16), 256, 0, stream>>>(QKV, VT);
  k_rope<<<49152, 256, 0, stream>>>(QKV, cosT, sinT);
  k_attn<<<dim3(32, 16, 2), 256, 0, stream>>>(QKV, VT, AttO);
  k_transpose<<<dim3(112, 128), 256, 0, stream>>>(Wo, Wot, 4096, 3584);
  k_gemm2<1><<<dim3(14, 16), 512, 0, stream>>>(AttO, Wot, d_out, 4096, 3584, 4096);
}

// Round 10
// 772.908 us; speedup vs baseline: 1.0220x; 1.0220x over previous
//
#include <hip/hip_runtime.h>
#include <stdint.h>

typedef unsigned short U16;
typedef float f32x4 __attribute__((ext_vector_type(4)));
typedef __bf16 bf16x8 __attribute__((ext_vector_type(8)));

static __device__ __forceinline__ U16 f2bf(float x) {
  union { float f; unsigned u; } v; v.f = x;
  unsigned r = v.u + 0x7FFFu + ((v.u >> 16) & 1u);
  return (U16)(r >> 16);
}
static __device__ __forceinline__ float bf2f(U16 h) {
  union { unsigned u; float f; } v; v.u = ((unsigned)h) << 16;
  return v.f;
}

static __device__ __forceinline__ void gload_lds16(const void* g, void* l) {
  __builtin_amdgcn_global_load_lds(
      (const __attribute__((address_space(1))) void*)g,
      (__attribute__((address_space(3))) void*)l, 16, 0, 0);
}

// ---------------- hidden (fp32) -> bf16 -------------------------------------
__global__ __launch_bounds__(256) void k_convert(const float* __restrict__ src,
                                                 U16* __restrict__ dst, long n) {
  long base = ((long)blockIdx.x * 256 + threadIdx.x) * 8;
  if (base >= n) return;
  const float4* s = (const float4*)(src + base);
  float4 a = s[0], b = s[1];
  U16 o[8] = { f2bf(a.x), f2bf(a.y), f2bf(a.z), f2bf(a.w),
               f2bf(b.x), f2bf(b.y), f2bf(b.z), f2bf(b.w) };
  *(uint4*)(dst + base) = *(const uint4*)o;
}

// ---------------- W[K][N] (fp32) -> Wt[N][K] bf16 ----------------------------
__global__ __launch_bounds__(256) void k_transpose(const float* __restrict__ src,
                                                   U16* __restrict__ dst,
                                                   int K, int N) {
  __shared__ U16 tile[32][33];
  int n0 = blockIdx.x * 32, k0 = blockIdx.y * 32;
  int tx = threadIdx.x & 31, ty = threadIdx.x >> 5;
#pragma unroll
  for (int r = 0; r < 4; ++r) {
    int k = k0 + ty + r * 8;
    tile[ty + r * 8][tx] = f2bf(src[(long)k * N + n0 + tx]);
  }
  __syncthreads();
#pragma unroll
  for (int r = 0; r < 4; ++r) {
    int n = n0 + ty + r * 8;
    dst[(long)n * K + k0 + tx] = tile[tx][ty + r * 8];
  }
}

// ---- V section of QKV -> VT tiled [bk][sTile=64][d=256][s32=32] bf16 -------
__global__ __launch_bounds__(256) void k_vtrans(const U16* __restrict__ QKV,
                                                U16* __restrict__ VT) {
  __shared__ U16 tile[32][33];
  int s0 = blockIdx.x * 32, d0 = blockIdx.y * 32, bk = blockIdx.z;
  int b = bk >> 3, kvh = bk & 7;
  int tx = threadIdx.x & 31, ty = threadIdx.x >> 5;
  const U16* src = QKV + (long)(b * 2048) * 8192 + 6144 + kvh * 256;
#pragma unroll
  for (int r = 0; r < 4; ++r) {
    int s = s0 + ty + r * 8;
    tile[ty + r * 8][tx] = src[(long)s * 8192 + d0 + tx];
  }
  __syncthreads();
  long tbase = ((long)bk * 64 + (s0 >> 5)) * 8192;   // 256*32 per tile
#pragma unroll
  for (int r = 0; r < 4; ++r) {
    int d = d0 + ty + r * 8;
    VT[tbase + d * 32 + tx] = tile[tx][ty + r * 8];
  }
}

// ---------------- RoPE tables (fp32) ----------------------------------------
__global__ __launch_bounds__(256) void k_rope_tables(float* __restrict__ cosT,
                                                     float* __restrict__ sinT) {
  int i = blockIdx.x * 256 + threadIdx.x;
  int s = i >> 7, d = i & 127;
  float freq = expf(-9.210340371976184f * (float)d / 128.0f);
  float ang = (float)s * freq;
  cosT[i] = cosf(ang);
  sinT[i] = sinf(ang);
}

// ---------------- RoPE in place on q,k sections of QKV ----------------------
__global__ __launch_bounds__(256) void k_rope(U16* __restrict__ qkv,
                                              const float* __restrict__ cosT,
                                              const float* __restrict__ sinT) {
  int i = blockIdx.x * 256 + threadIdx.x;
  int d = i & 127;
  int hh = (i >> 7) % 24;
  int row = i / 3072;
  int s = row & 2047;
  int col = (hh < 16) ? hh * 256 + d : 4096 + (hh - 16) * 256 + d;
  long base = (long)row * 8192 + col;
  float c = cosT[s * 128 + d], sn = sinT[s * 128 + d];
  float x1 = bf2f(qkv[base]), x2 = bf2f(qkv[base + 128]);
  qkv[base]       = f2bf(x1 * c - x2 * sn);
  qkv[base + 128] = f2bf(x2 * c + x1 * sn);
}

// ---------------- GEMM v4: 256x256, 8 waves, 3-deep pipeline, 2-PHASE -------
// Fragment-linear LDS (r9). Per BK=32 tile, two phases:
//  ph0: ds_read B(4)+A-low(4) | issue 2 A-gloads(t+2) | bar | 16 MFMA | bar
//  ph1: ds_read A-high(4)     | issue 2 B-gloads(t+2) | bar | 16 MFMA
//       | vmcnt(4) (t+1 resident) | bar
// Reads issued pre-barrier overlap the previous MFMA cluster; read bursts
// halve; waves stay lockstep (T3 minimum-2-phase + T4 counted vmcnt + T5).
template <int F32OUT>
__global__ __launch_bounds__(512, 2) void k_gemm2(const U16* __restrict__ A,
                                                  const U16* __restrict__ Bt,
                                                  void* __restrict__ Cv,
                                                  int M, int N, int K) {
  __shared__ __align__(16) U16 Ab[3][256 * 32];
  __shared__ __align__(16) U16 Bb[3][256 * 32];
  int nwg = gridDim.x * gridDim.y;
  int flat = blockIdx.y * gridDim.x + blockIdx.x;
  int cpx = nwg >> 3;
  int swz = (flat & 7) * cpx + (flat >> 3);
  int bx = swz % gridDim.x, by = swz / gridDim.x;
  int t = threadIdx.x, lane = t & 63, w = t >> 6;
  int m0 = by * 256, n0 = bx * 256;
  int wm = w >> 2, wn = w & 3;
  int l15 = lane & 15, l4 = lane >> 4;

  f32x4 acc[8][4] = {};

  // staging source (fragment-linear): issue covers fragment f = w (+8);
  // lane covers row f*16 + (lane>>2), bf16 col (lane&3)*8.
  int sr = lane >> 2, sc = (lane & 3) * 8;
  const U16* gA0 = A + (long)(m0 + w * 16 + sr) * K + sc;
  const U16* gA1 = A + (long)(m0 + 128 + w * 16 + sr) * K + sc;
  const U16* gB0 = Bt + (long)(n0 + w * 16 + sr) * K + sc;
  const U16* gB1 = Bt + (long)(n0 + 128 + w * 16 + sr) * K + sc;

  auto stageA = [&](int buf, int kt) {
    long k0 = (long)kt * 32;
    gload_lds16(gA0 + k0, (char*)&Ab[buf][0] + w * 1024);
    gload_lds16(gA1 + k0, (char*)&Ab[buf][0] + 8192 + w * 1024);
  };
  auto stageB = [&](int buf, int kt) {
    long k0 = (long)kt * 32;
    gload_lds16(gB0 + k0, (char*)&Bb[buf][0] + w * 1024);
    gload_lds16(gB1 + k0, (char*)&Bb[buf][0] + 8192 + w * 1024);
  };

  int lofs = (l15 * 4 + l4) * 16;

  // monolithic compute for the 2-tile epilogue
  auto compute_full = [&](int buf) {
    const char* Ac = (const char*)&Ab[buf][0] + lofs;
    const char* Bc = (const char*)&Bb[buf][0] + lofs;
    bf16x8 af[8], bb[4];
#pragma unroll
    for (int m = 0; m < 8; ++m)
      af[m] = *(const bf16x8*)(Ac + (wm * 8 + m) * 1024);
#pragma unroll
    for (int n = 0; n < 4; ++n)
      bb[n] = *(const bf16x8*)(Bc + (wn * 4 + n) * 1024);
    __builtin_amdgcn_s_setprio(1);
#pragma unroll
    for (int m = 0; m < 8; ++m)
#pragma unroll
      for (int n = 0; n < 4; ++n)
        acc[m][n] = __builtin_amdgcn_mfma_f32_16x16x32_bf16(af[m], bb[n], acc[m][n], 0, 0, 0);
    __builtin_amdgcn_s_setprio(0);
  };

  int T = K >> 5;
  stageA(0, 0); stageB(0, 0);
  stageA(1, 1); stageB(1, 1);
  asm volatile("s_waitcnt vmcnt(4)" ::: "memory");
  __builtin_amdgcn_sched_barrier(0);
  __builtin_amdgcn_s_barrier();
  __builtin_amdgcn_sched_barrier(0);

  int cur = 0, stb = 2;
  for (int kt = 0; kt < T - 2; ++kt) {
    const char* Ac = (const char*)&Ab[cur][0] + lofs;
    const char* Bc = (const char*)&Bb[cur][0] + lofs;
    bf16x8 af[4], bb[4];
    // ---- phase 0: B + A-low reads | A-gloads | bar | MFMA m0..3 | bar ----
#pragma unroll
    for (int n = 0; n < 4; ++n)
      bb[n] = *(const bf16x8*)(Bc + (wn * 4 + n) * 1024);
#pragma unroll
    for (int m = 0; m < 4; ++m)
      af[m] = *(const bf16x8*)(Ac + (wm * 8 + m) * 1024);
    stageA(stb, kt + 2);
    __builtin_amdgcn_sched_barrier(0);
    __builtin_amdgcn_s_barrier();
    __builtin_amdgcn_sched_barrier(0);
    __builtin_amdgcn_s_setprio(1);
#pragma unroll
    for (int m = 0; m < 4; ++m)
#pragma unroll
      for (int n = 0; n < 4; ++n)
        acc[m][n] = __builtin_amdgcn_mfma_f32_16x16x32_bf16(af[m], bb[n], acc[m][n], 0, 0, 0);
    __builtin_amdgcn_s_setprio(0);
    __builtin_amdgcn_sched_barrier(0);
    __builtin_amdgcn_s_barrier();
    __builtin_amdgcn_sched_barrier(0);
    // ---- phase 1: A-high reads | B-gloads | bar | MFMA m4..7 | vmcnt | bar -
    bf16x8 ah[4];
#pragma unroll
    for (int m = 0; m < 4; ++m)
      ah[m] = *(const bf16x8*)(Ac + (wm * 8 + 4 + m) * 1024);
    stageB(stb, kt + 2);
    __builtin_amdgcn_sched_barrier(0);
    __builtin_amdgcn_s_barrier();
    __builtin_amdgcn_sched_barrier(0);
    __builtin_amdgcn_s_setprio(1);
#pragma unroll
    for (int m = 0; m < 4; ++m)
#pragma unroll
      for (int n = 0; n < 4; ++n)
        acc[4 + m][n] = __builtin_amdgcn_mfma_f32_16x16x32_bf16(ah[m], bb[n], acc[4 + m][n], 0, 0, 0);
    __builtin_amdgcn_s_setprio(0);
    asm volatile("s_waitcnt vmcnt(4)" ::: "memory");
    __builtin_amdgcn_sched_barrier(0);
    __builtin_amdgcn_s_barrier();
    __builtin_amdgcn_sched_barrier(0);
    cur = (cur + 1 == 3) ? 0 : cur + 1;
    stb = (stb + 1 == 3) ? 0 : stb + 1;
  }
  compute_full(cur);                             // tile T-2
  asm volatile("s_waitcnt vmcnt(0)" ::: "memory");
  __builtin_amdgcn_sched_barrier(0);
  __builtin_amdgcn_s_barrier();
  __builtin_amdgcn_sched_barrier(0);
  cur = (cur + 1 == 3) ? 0 : cur + 1;
  compute_full(cur);                             // tile T-1

  // epilogue
#pragma unroll
  for (int m = 0; m < 8; ++m)
#pragma unroll
    for (int jj = 0; jj < 4; ++jj) {
      int row = m0 + wm * 128 + m * 16 + l4 * 4 + jj;
      if (F32OUT) {
        float* cp = (float*)Cv + (long)row * N + n0 + wn * 64 + l15;
#pragma unroll
        for (int n = 0; n < 4; ++n) cp[n * 16] = acc[m][n][jj];
      } else {
        U16* cp = (U16*)Cv + (long)row * N + n0 + wn * 64 + l15;
#pragma unroll
        for (int n = 0; n < 4; ++n) cp[n * 16] = f2bf(acc[m][n][jj]);
      }
    }
}

// ---------------- banded GQA attention (v5, unchanged) ----------------------
__global__ __launch_bounds__(256) void k_attn(const U16* __restrict__ QKV,
                                              const U16* __restrict__ VT,
                                              U16* __restrict__ O) {
  __shared__ __align__(16) U16 Ks[2][32 * 256];
  __shared__ __align__(16) U16 Vs[2][256 * 32];
  __shared__ __align__(16) U16 Plds[4][16 * 40];
  int t = threadIdx.x, lane = t & 63, w = t >> 6;
  int flat = blockIdx.x + 32 * (blockIdx.y + 16 * blockIdx.z);
  int l = (flat & 7) * 128 + (flat >> 3);
  int qb = l & 31, h = (l >> 5) & 15, b = l >> 9;
  int s0 = qb * 64;
  int kvh = h >> 1;
  long rowOff = (long)b * 2048 * 8192;
  const U16* Qb = QKV + rowOff + h * 256;
  const U16* Kb = QKV + rowOff + 4096 + kvh * 256;
  const U16* VTb = VT + (long)(b * 8 + kvh) * 64 * 8192;

  int l15 = lane & 15, l4 = lane >> 4;

  bf16x8 qf[8];
  {
    const U16* qp = Qb + (long)(s0 + w * 16 + l15) * 8192 + l4 * 8;
#pragma unroll
    for (int kc = 0; kc < 8; ++kc) qf[kc] = *(const bf16x8*)(qp + kc * 32);
  }
  asm volatile("s_waitcnt vmcnt(0)" ::: "memory");

  f32x4 acc[16] = {};
  float mrun = -1e30f, lrun = 0.0f;
  int qpos = s0 + w * 16 + l15;

  int kstart = s0 - 1024; if (kstart < 0) kstart = 0;
  int kend = s0 + 64 + 1024; if (kend > 2048) kend = 2048;

  auto stage = [&](int buf, int k0) {
#pragma unroll
    for (int i = 0; i < 4; ++i) {
      int g = i * 256 + t;
      int row = g >> 5, c = g & 31;
      int cs = c ^ (row & 7);
      gload_lds16(Kb + (long)(k0 + row) * 8192 + cs * 8,
                  (char*)&Ks[buf][0] + i * 4096 + w * 1024);
    }
    const U16* vtile = VTb + (long)(k0 >> 5) * 8192;
#pragma unroll
    for (int i = 0; i < 4; ++i) {
      int g = i * 256 + t;
      int d = g >> 2, c = g & 3;
      int cs = c ^ ((d >> 1) & 3);
      gload_lds16(vtile + d * 32 + cs * 8,
                  (char*)&Vs[buf][0] + i * 4096 + w * 1024);
    }
  };

  auto compute = [&](int buf, int k0) {
    f32x4 sAcc[2] = {};
    __builtin_amdgcn_s_setprio(1);
#pragma unroll
    for (int kc = 0; kc < 8; ++kc) {
      int c0 = ((kc * 4 + l4) ^ (l15 & 7)) * 8;
      bf16x8 a0 = *(const bf16x8*)&Ks[buf][l15 * 256 + c0];
      bf16x8 a1 = *(const bf16x8*)&Ks[buf][(16 + l15) * 256 + c0];
      sAcc[0] = __builtin_amdgcn_mfma_f32_16x16x32_bf16(a0, qf[kc], sAcc[0], 0, 0, 0);
      sAcc[1] = __builtin_amdgcn_mfma_f32_16x16x32_bf16(a1, qf[kc], sAcc[1], 0, 0, 0);
    }
    __builtin_amdgcn_s_setprio(0);
    float sv[8];
#pragma unroll
    for (int mp = 0; mp < 2; ++mp)
#pragma unroll
      for (int jj = 0; jj < 4; ++jj) {
        int key = k0 + mp * 16 + l4 * 4 + jj;
        float x = sAcc[mp][jj] * 0.00125f;
        float ex = __expf(2.0f * x);
        float z = 50.0f * (ex - 1.0f) / (ex + 1.0f);
        int dd = qpos - key;
        if (dd < -1024 || dd > 1024) z = -3e38f;
        sv[mp * 4 + jj] = z;
      }
    float tmax = sv[0];
#pragma unroll
    for (int i = 1; i < 8; ++i) tmax = fmaxf(tmax, sv[i]);
    tmax = fmaxf(tmax, __shfl_xor(tmax, 16));
    tmax = fmaxf(tmax, __shfl_xor(tmax, 32));
    bool skipall = __all((tmax <= mrun + 8.0f) ? 1 : 0) != 0;
    float mnew = skipall ? mrun : fmaxf(mrun, tmax);
    float pex[8];
    float psum = 0.0f;
#pragma unroll
    for (int i = 0; i < 8; ++i) { pex[i] = __expf(sv[i] - mnew); psum += pex[i]; }
    psum += __shfl_xor(psum, 16);
    psum += __shfl_xor(psum, 32);
    if (skipall) {
      lrun += psum;
    } else {
      float esc = __expf(mrun - mnew);
      f32x4 ev;
#pragma unroll
      for (int jj = 0; jj < 4; ++jj) ev[jj] = __shfl(esc, l4 * 4 + jj);
#pragma unroll
      for (int n = 0; n < 16; ++n) acc[n] *= ev;
      lrun = lrun * esc + psum;
      mrun = mnew;
    }
#pragma unroll
    for (int mp = 0; mp < 2; ++mp)
#pragma unroll
      for (int j2 = 0; j2 < 2; ++j2) {
        unsigned lo = f2bf(pex[mp * 4 + j2 * 2]);
        unsigned hi = f2bf(pex[mp * 4 + j2 * 2 + 1]);
        *(unsigned*)&Plds[w][l15 * 40 + mp * 16 + l4 * 4 + j2 * 2] = lo | (hi << 16);
      }
    asm volatile("s_waitcnt lgkmcnt(0)" ::: "memory");
    __builtin_amdgcn_sched_barrier(0);
    bf16x8 pa = *(const bf16x8*)&Plds[w][l15 * 40 + l4 * 8];
    __builtin_amdgcn_s_setprio(1);
#pragma unroll
    for (int n = 0; n < 16; ++n) {
      int d = n * 16 + l15;
      int c = (l4 ^ ((d >> 1) & 3)) * 8;
      bf16x8 vb = *(const bf16x8*)&Vs[buf][d * 32 + c];
      acc[n] = __builtin_amdgcn_mfma_f32_16x16x32_bf16(pa, vb, acc[n], 0, 0, 0);
    }
    __builtin_amdgcn_s_setprio(0);
  };

  int cur = 0;
  stage(0, kstart);
  for (int k0 = kstart; k0 < kend - 32; k0 += 32) {
    stage(cur ^ 1, k0 + 32);
    asm volatile("s_waitcnt vmcnt(8)" ::: "memory");
    __builtin_amdgcn_s_barrier();
    __builtin_amdgcn_sched_barrier(0);
    compute(cur, k0);
    __builtin_amdgcn_s_barrier();
    cur ^= 1;
  }
  asm volatile("s_waitcnt vmcnt(0)" ::: "memory");
  __builtin_amdgcn_s_barrier();
  __builtin_amdgcn_sched_barrier(0);
  compute(cur, kend - 32);

  f32x4 linv;
#pragma unroll
  for (int jj = 0; jj < 4; ++jj) linv[jj] = 1.0f / __shfl(lrun, l4 * 4 + jj);
#pragma unroll
  for (int jj = 0; jj < 4; ++jj) {
    int row = s0 + w * 16 + l4 * 4 + jj;
    U16* op = O + ((long)b * 2048 + row) * 4096 + h * 256 + l15;
#pragma unroll
    for (int n = 0; n < 16; ++n) op[n * 16] = f2bf(acc[n][jj] * linv[jj]);
  }
}

// ----------------------------------------------------------------------------
extern "C" void kernel_launch(void* const* d_in, const int* in_sizes, int n_in,
                              void* d_out, int out_size, void* d_ws, size_t ws_size,
                              hipStream_t stream) {
  if (n_in < 5) return;
  const float* hid = (const float*)d_in[0];
  const float* Wq  = (const float*)d_in[1];
  const float* Wk  = (const float*)d_in[2];
  const float* Wv  = (const float*)d_in[3];
  const float* Wo  = (const float*)d_in[4];

  char* ws = (char*)d_ws;
  size_t off = 0;
  auto alloc = [&](size_t bytes) {
    char* p = ws + off;
    off += (bytes + 255) & ~(size_t)255;
    return p;
  };
  float* cosT = (float*)alloc((size_t)2048 * 128 * 4);
  float* sinT = (float*)alloc((size_t)2048 * 128 * 4);
  U16*   Xb   = (U16*)alloc((size_t)4096 * 3584 * 2);   // reused: VT, then Wot
  U16*   Wt   = (U16*)alloc((size_t)8192 * 3584 * 2);   // reused: AttO
  U16*   QKV  = (U16*)alloc((size_t)4096 * 8192 * 2);
  if (off > ws_size) return;
  U16* VT   = Xb;                 // 16*64*8192*2 B = 16.8 MB < |Xb|
  U16* Wot  = Xb;                 // written after attn (VT dead by then)
  U16* AttO = Wt;

  k_convert<<<7168, 256, 0, stream>>>(hid, Xb, (long)4096 * 3584);
  k_transpose<<<dim3(128, 112), 256, 0, stream>>>(Wq, Wt, 3584, 4096);
  k_transpose<<<dim3(64, 112), 256, 0, stream>>>(Wk, Wt + (size_t)4096 * 3584, 3584, 2048);
  k_transpose<<<dim3(64, 112), 256, 0, stream>>>(Wv, Wt + (size_t)6144 * 3584, 3584, 2048);
  k_rope_tables<<<1024, 256, 0, stream>>>(cosT, sinT);
  k_gemm2<0><<<dim3(32, 16), 512, 0, stream>>>(Xb, Wt, QKV, 4096, 8192, 3584);
  k_vtrans<<<dim3(64, 8, 16), 256, 0, stream>>>(QKV, VT);
  k_rope<<<49152, 256, 0, stream>>>(QKV, cosT, sinT);
  k_attn<<<dim3(32, 16, 2), 256, 0, stream>>>(QKV, VT, AttO);
  k_transpose<<<dim3(112, 128), 256, 0, stream>>>(Wo, Wot, 4096, 3584);
  k_gemm2<1><<<dim3(14, 16), 512, 0, stream>>>(AttO, Wot, d_out, 4096, 3584, 4096);
}

// Round 11
// 700.947 us; speedup vs baseline: 1.1269x; 1.1027x over previous
//
#include <hip/hip_runtime.h>
#include <stdint.h>

typedef unsigned short U16;
typedef float f32x4 __attribute__((ext_vector_type(4)));
typedef __bf16 bf16x8 __attribute__((ext_vector_type(8)));

static __device__ __forceinline__ U16 f2bf(float x) {
  union { float f; unsigned u; } v; v.f = x;
  unsigned r = v.u + 0x7FFFu + ((v.u >> 16) & 1u);
  return (U16)(r >> 16);
}
static __device__ __forceinline__ float bf2f(U16 h) {
  union { unsigned u; float f; } v; v.u = ((unsigned)h) << 16;
  return v.f;
}

static __device__ __forceinline__ void gload_lds16(const void* g, void* l) {
  __builtin_amdgcn_global_load_lds(
      (const __attribute__((address_space(1))) void*)g,
      (__attribute__((address_space(3))) void*)l, 16, 0, 0);
}

#define SBAR() __builtin_amdgcn_sched_barrier(0)

// ---------------- hidden (fp32) -> bf16 -------------------------------------
__global__ __launch_bounds__(256) void k_convert(const float* __restrict__ src,
                                                 U16* __restrict__ dst, long n) {
  long base = ((long)blockIdx.x * 256 + threadIdx.x) * 8;
  if (base >= n) return;
  const float4* s = (const float4*)(src + base);
  float4 a = s[0], b = s[1];
  U16 o[8] = { f2bf(a.x), f2bf(a.y), f2bf(a.z), f2bf(a.w),
               f2bf(b.x), f2bf(b.y), f2bf(b.z), f2bf(b.w) };
  *(uint4*)(dst + base) = *(const uint4*)o;
}

// ---------------- W[K][N] (fp32) -> Wt[N][K] bf16 ----------------------------
__global__ __launch_bounds__(256) void k_transpose(const float* __restrict__ src,
                                                   U16* __restrict__ dst,
                                                   int K, int N) {
  __shared__ U16 tile[32][33];
  int n0 = blockIdx.x * 32, k0 = blockIdx.y * 32;
  int tx = threadIdx.x & 31, ty = threadIdx.x >> 5;
#pragma unroll
  for (int r = 0; r < 4; ++r) {
    int k = k0 + ty + r * 8;
    tile[ty + r * 8][tx] = f2bf(src[(long)k * N + n0 + tx]);
  }
  __syncthreads();
#pragma unroll
  for (int r = 0; r < 4; ++r) {
    int n = n0 + ty + r * 8;
    dst[(long)n * K + k0 + tx] = tile[tx][ty + r * 8];
  }
}

// ---- V section of QKV -> VT tiled [bk][sTile=64][d=256][s32=32] bf16 -------
__global__ __launch_bounds__(256) void k_vtrans(const U16* __restrict__ QKV,
                                                U16* __restrict__ VT) {
  __shared__ U16 tile[32][33];
  int s0 = blockIdx.x * 32, d0 = blockIdx.y * 32, bk = blockIdx.z;
  int b = bk >> 3, kvh = bk & 7;
  int tx = threadIdx.x & 31, ty = threadIdx.x >> 5;
  const U16* src = QKV + (long)(b * 2048) * 8192 + 6144 + kvh * 256;
#pragma unroll
  for (int r = 0; r < 4; ++r) {
    int s = s0 + ty + r * 8;
    tile[ty + r * 8][tx] = src[(long)s * 8192 + d0 + tx];
  }
  __syncthreads();
  long tbase = ((long)bk * 64 + (s0 >> 5)) * 8192;
#pragma unroll
  for (int r = 0; r < 4; ++r) {
    int d = d0 + ty + r * 8;
    VT[tbase + d * 32 + tx] = tile[tx][ty + r * 8];
  }
}

// ---------------- RoPE tables (fp32) ----------------------------------------
__global__ __launch_bounds__(256) void k_rope_tables(float* __restrict__ cosT,
                                                     float* __restrict__ sinT) {
  int i = blockIdx.x * 256 + threadIdx.x;
  int s = i >> 7, d = i & 127;
  float freq = expf(-9.210340371976184f * (float)d / 128.0f);
  float ang = (float)s * freq;
  cosT[i] = cosf(ang);
  sinT[i] = sinf(ang);
}

// ---------------- RoPE in place on q,k sections of QKV ----------------------
__global__ __launch_bounds__(256) void k_rope(U16* __restrict__ qkv,
                                              const float* __restrict__ cosT,
                                              const float* __restrict__ sinT) {
  int i = blockIdx.x * 256 + threadIdx.x;
  int d = i & 127;
  int hh = (i >> 7) % 24;
  int row = i / 3072;
  int s = row & 2047;
  int col = (hh < 16) ? hh * 256 + d : 4096 + (hh - 16) * 256 + d;
  long base = (long)row * 8192 + col;
  float c = cosT[s * 128 + d], sn = sinT[s * 128 + d];
  float x1 = bf2f(qkv[base]), x2 = bf2f(qkv[base + 128]);
  qkv[base]       = f2bf(x1 * c - x2 * sn);
  qkv[base + 128] = f2bf(x2 * c + x1 * sn);
}

// ---------------- GEMM v5: 256x256, BK=64, 8 waves, 8-PHASE (m201 port) -----
// Fragment-linear LDS halves: Asl/Bsl[buf][half] = 16 sub-blocks of 1KB;
// sub-block s = f*2+kk holds rows f*16..+15 (within half) x k kk*32..+31,
// granule (l15*4+l4)*16B. Quad order (0,0),(0,1),(1,1),(1,0); per-phase reads
// {12,4,8,0}; stage one half-tile per phase (ledger-verified overwrite-after-
// last-read); vmcnt(4) only at P3/P7. K-order per C element unchanged ->
// bitwise-identical output vs rounds 7-10.
template <int F32OUT>
__global__ __launch_bounds__(512, 1) void k_gemm8(const U16* __restrict__ A,
                                                  const U16* __restrict__ Bt,
                                                  void* __restrict__ Cv,
                                                  int M, int N, int K) {
  __shared__ __align__(16) U16 Asl[2][2][128 * 64];
  __shared__ __align__(16) U16 Bsl[2][2][128 * 64];
  int nwg = gridDim.x * gridDim.y;
  int flat = blockIdx.y * gridDim.x + blockIdx.x;
  int cpx = nwg >> 3;
  int swz = (flat & 7) * cpx + (flat >> 3);
  int bx = swz % gridDim.x, by = swz / gridDim.x;
  int t = threadIdx.x, lane = t & 63, w = t >> 6;
  int m0 = by * 256, n0 = bx * 256;
  int wm = w >> 2, wn = w & 3;
  int l15 = lane & 15, l4 = lane >> 4;
  int lofs = (l15 * 4 + l4) * 16;

  f32x4 acc[8][4] = {};
  int T = K >> 6;

  // staging: wave-instruction (j,w) fills sub-block sblk = j*8+w of a half;
  // lane covers row f*16 + (lane>>2), k = kk*32 + (lane&3)*8.
  int sr = lane >> 2, sc4 = (lane & 3) * 8;
  int fA0 = (w >> 1) * 16 + sr, kA0 = (w & 1) * 32 + sc4;          // j=0
  int fA1 = ((8 + w) >> 1) * 16 + sr, kA1 = ((8 + w) & 1) * 32 + sc4;  // j=1
  const U16* aj0 = A + (long)(m0 + fA0) * K + kA0;
  const U16* aj1 = A + (long)(m0 + fA1) * K + kA1;
  const U16* bj0 = Bt + (long)(n0 + fA0) * K + kA0;
  const U16* bj1 = Bt + (long)(n0 + fA1) * K + kA1;

  auto stageH = [&](int op, int kt, int h) {
    int buf = kt & 1;
    int ktc = (kt < T) ? kt : 0;
    long off = (long)ktc * 64 + (long)h * 128 * K;
    if (op == 0) {
      gload_lds16(aj0 + off, (char*)&Asl[buf][h][0] + w * 1024);
      gload_lds16(aj1 + off, (char*)&Asl[buf][h][0] + 8192 + w * 1024);
    } else {
      gload_lds16(bj0 + off, (char*)&Bsl[buf][h][0] + w * 1024);
      gload_lds16(bj1 + off, (char*)&Bsl[buf][h][0] + 8192 + w * 1024);
    }
  };

  bf16x8 Ar[4][2], Bq[2][2][2];   // Ar[i][kk]; Bq[c][j][kk]

  auto readA = [&](int buf, int r) {
    const char* base = (const char*)&Asl[buf][wm][0] + lofs;
#pragma unroll
    for (int i = 0; i < 4; ++i)
#pragma unroll
      for (int kk = 0; kk < 2; ++kk)
        Ar[i][kk] = *(const bf16x8*)(base + ((r * 4 + i) * 2 + kk) * 1024);
  };
  auto readB = [&](int buf, int c) {
    const char* base = (const char*)&Bsl[buf][wn >> 1][0] + lofs;
#pragma unroll
    for (int j = 0; j < 2; ++j)
#pragma unroll
      for (int kk = 0; kk < 2; ++kk)
        Bq[c][j][kk] = *(const bf16x8*)(base + (((wn & 1) * 4 + c * 2 + j) * 2 + kk) * 1024);
  };
  auto mfmaQ = [&](int r, int c) {
    __builtin_amdgcn_s_setprio(1);
#pragma unroll
    for (int i = 0; i < 4; ++i)
#pragma unroll
      for (int j = 0; j < 2; ++j) {
        int m = r * 4 + i, n = c * 2 + j;
        acc[m][n] = __builtin_amdgcn_mfma_f32_16x16x32_bf16(Ar[i][0], Bq[c][j][0], acc[m][n], 0, 0, 0);
        acc[m][n] = __builtin_amdgcn_mfma_f32_16x16x32_bf16(Ar[i][1], Bq[c][j][1], acc[m][n], 0, 0, 0);
      }
    __builtin_amdgcn_s_setprio(0);
  };

#define PH_SYNC() do { SBAR(); __builtin_amdgcn_s_barrier(); \
    asm volatile("s_waitcnt lgkmcnt(0)" ::: "memory"); SBAR(); } while (0)
#define PH_END() do { SBAR(); __builtin_amdgcn_s_barrier(); SBAR(); } while (0)

  // prologue: tile0 all 4 halves, tile1 Bh0+Ah0; vmcnt(4); barrier
  stageH(0, 0, 0); stageH(0, 0, 1); stageH(1, 0, 0); stageH(1, 0, 1);
  stageH(1, 1, 0); stageH(0, 1, 0);
  asm volatile("s_waitcnt vmcnt(4)" ::: "memory");
  SBAR(); __builtin_amdgcn_s_barrier(); SBAR();

  for (int base = 0; base < T; base += 2) {
    // ---- P0: q(0,0) of tile base (buf0) ----
    readA(0, 0); readB(0, 0);
    stageH(0, base + 1, 1);
    PH_SYNC(); mfmaQ(0, 0); PH_END();
    // ---- P1: q(0,1) ----
    readB(0, 1);
    stageH(1, base + 1, 1);
    PH_SYNC(); mfmaQ(0, 1); PH_END();
    // ---- P2: q(1,1) ----
    readA(0, 1);
    stageH(1, base + 2, 0);
    PH_SYNC(); mfmaQ(1, 1); PH_END();
    // ---- P3: q(1,0) ----
    stageH(0, base + 2, 0);
    PH_SYNC(); mfmaQ(1, 0);
    asm volatile("s_waitcnt vmcnt(4)" ::: "memory");
    PH_END();
    // ---- P4: q(0,0) of tile base+1 (buf1) ----
    readA(1, 0); readB(1, 0);
    stageH(0, base + 2, 1);
    PH_SYNC(); mfmaQ(0, 0); PH_END();
    // ---- P5: q(0,1) ----
    readB(1, 1);
    stageH(1, base + 2, 1);
    PH_SYNC(); mfmaQ(0, 1); PH_END();
    // ---- P6: q(1,1) ----
    readA(1, 1);
    stageH(1, base + 3, 0);
    PH_SYNC(); mfmaQ(1, 1); PH_END();
    // ---- P7: q(1,0) ----
    stageH(0, base + 3, 0);
    PH_SYNC(); mfmaQ(1, 0);
    asm volatile("s_waitcnt vmcnt(4)" ::: "memory");
    PH_END();
  }

#undef PH_SYNC
#undef PH_END

  // epilogue
#pragma unroll
  for (int m = 0; m < 8; ++m)
#pragma unroll
    for (int jj = 0; jj < 4; ++jj) {
      int row = m0 + wm * 128 + m * 16 + l4 * 4 + jj;
      if (F32OUT) {
        float* cp = (float*)Cv + (long)row * N + n0 + wn * 64 + l15;
#pragma unroll
        for (int n = 0; n < 4; ++n) cp[n * 16] = acc[m][n][jj];
      } else {
        U16* cp = (U16*)Cv + (long)row * N + n0 + wn * 64 + l15;
#pragma unroll
        for (int n = 0; n < 4; ++n) cp[n * 16] = f2bf(acc[m][n][jj]);
      }
    }
}

// ---------------- banded GQA attention (v5, unchanged) ----------------------
__global__ __launch_bounds__(256) void k_attn(const U16* __restrict__ QKV,
                                              const U16* __restrict__ VT,
                                              U16* __restrict__ O) {
  __shared__ __align__(16) U16 Ks[2][32 * 256];
  __shared__ __align__(16) U16 Vs[2][256 * 32];
  __shared__ __align__(16) U16 Plds[4][16 * 40];
  int t = threadIdx.x, lane = t & 63, w = t >> 6;
  int flat = blockIdx.x + 32 * (blockIdx.y + 16 * blockIdx.z);
  int l = (flat & 7) * 128 + (flat >> 3);
  int qb = l & 31, h = (l >> 5) & 15, b = l >> 9;
  int s0 = qb * 64;
  int kvh = h >> 1;
  long rowOff = (long)b * 2048 * 8192;
  const U16* Qb = QKV + rowOff + h * 256;
  const U16* Kb = QKV + rowOff + 4096 + kvh * 256;
  const U16* VTb = VT + (long)(b * 8 + kvh) * 64 * 8192;

  int l15 = lane & 15, l4 = lane >> 4;

  bf16x8 qf[8];
  {
    const U16* qp = Qb + (long)(s0 + w * 16 + l15) * 8192 + l4 * 8;
#pragma unroll
    for (int kc = 0; kc < 8; ++kc) qf[kc] = *(const bf16x8*)(qp + kc * 32);
  }
  asm volatile("s_waitcnt vmcnt(0)" ::: "memory");

  f32x4 acc[16] = {};
  float mrun = -1e30f, lrun = 0.0f;
  int qpos = s0 + w * 16 + l15;

  int kstart = s0 - 1024; if (kstart < 0) kstart = 0;
  int kend = s0 + 64 + 1024; if (kend > 2048) kend = 2048;

  auto stage = [&](int buf, int k0) {
#pragma unroll
    for (int i = 0; i < 4; ++i) {
      int g = i * 256 + t;
      int row = g >> 5, c = g & 31;
      int cs = c ^ (row & 7);
      gload_lds16(Kb + (long)(k0 + row) * 8192 + cs * 8,
                  (char*)&Ks[buf][0] + i * 4096 + w * 1024);
    }
    const U16* vtile = VTb + (long)(k0 >> 5) * 8192;
#pragma unroll
    for (int i = 0; i < 4; ++i) {
      int g = i * 256 + t;
      int d = g >> 2, c = g & 3;
      int cs = c ^ ((d >> 1) & 3);
      gload_lds16(vtile + d * 32 + cs * 8,
                  (char*)&Vs[buf][0] + i * 4096 + w * 1024);
    }
  };

  auto compute = [&](int buf, int k0) {
    f32x4 sAcc[2] = {};
    __builtin_amdgcn_s_setprio(1);
#pragma unroll
    for (int kc = 0; kc < 8; ++kc) {
      int c0 = ((kc * 4 + l4) ^ (l15 & 7)) * 8;
      bf16x8 a0 = *(const bf16x8*)&Ks[buf][l15 * 256 + c0];
      bf16x8 a1 = *(const bf16x8*)&Ks[buf][(16 + l15) * 256 + c0];
      sAcc[0] = __builtin_amdgcn_mfma_f32_16x16x32_bf16(a0, qf[kc], sAcc[0], 0, 0, 0);
      sAcc[1] = __builtin_amdgcn_mfma_f32_16x16x32_bf16(a1, qf[kc], sAcc[1], 0, 0, 0);
    }
    __builtin_amdgcn_s_setprio(0);
    float sv[8];
#pragma unroll
    for (int mp = 0; mp < 2; ++mp)
#pragma unroll
      for (int jj = 0; jj < 4; ++jj) {
        int key = k0 + mp * 16 + l4 * 4 + jj;
        float x = sAcc[mp][jj] * 0.00125f;
        float ex = __expf(2.0f * x);
        float z = 50.0f * (ex - 1.0f) / (ex + 1.0f);
        int dd = qpos - key;
        if (dd < -1024 || dd > 1024) z = -3e38f;
        sv[mp * 4 + jj] = z;
      }
    float tmax = sv[0];
#pragma unroll
    for (int i = 1; i < 8; ++i) tmax = fmaxf(tmax, sv[i]);
    tmax = fmaxf(tmax, __shfl_xor(tmax, 16));
    tmax = fmaxf(tmax, __shfl_xor(tmax, 32));
    bool skipall = __all((tmax <= mrun + 8.0f) ? 1 : 0) != 0;
    float mnew = skipall ? mrun : fmaxf(mrun, tmax);
    float pex[8];
    float psum = 0.0f;
#pragma unroll
    for (int i = 0; i < 8; ++i) { pex[i] = __expf(sv[i] - mnew); psum += pex[i]; }
    psum += __shfl_xor(psum, 16);
    psum += __shfl_xor(psum, 32);
    if (skipall) {
      lrun += psum;
    } else {
      float esc = __expf(mrun - mnew);
      f32x4 ev;
#pragma unroll
      for (int jj = 0; jj < 4; ++jj) ev[jj] = __shfl(esc, l4 * 4 + jj);
#pragma unroll
      for (int n = 0; n < 16; ++n) acc[n] *= ev;
      lrun = lrun * esc + psum;
      mrun = mnew;
    }
#pragma unroll
    for (int mp = 0; mp < 2; ++mp)
#pragma unroll
      for (int j2 = 0; j2 < 2; ++j2) {
        unsigned lo = f2bf(pex[mp * 4 + j2 * 2]);
        unsigned hi = f2bf(pex[mp * 4 + j2 * 2 + 1]);
        *(unsigned*)&Plds[w][l15 * 40 + mp * 16 + l4 * 4 + j2 * 2] = lo | (hi << 16);
      }
    asm volatile("s_waitcnt lgkmcnt(0)" ::: "memory");
    __builtin_amdgcn_sched_barrier(0);
    bf16x8 pa = *(const bf16x8*)&Plds[w][l15 * 40 + l4 * 8];
    __builtin_amdgcn_s_setprio(1);
#pragma unroll
    for (int n = 0; n < 16; ++n) {
      int d = n * 16 + l15;
      int c = (l4 ^ ((d >> 1) & 3)) * 8;
      bf16x8 vb = *(const bf16x8*)&Vs[buf][d * 32 + c];
      acc[n] = __builtin_amdgcn_mfma_f32_16x16x32_bf16(pa, vb, acc[n], 0, 0, 0);
    }
    __builtin_amdgcn_s_setprio(0);
  };

  int cur = 0;
  stage(0, kstart);
  for (int k0 = kstart; k0 < kend - 32; k0 += 32) {
    stage(cur ^ 1, k0 + 32);
    asm volatile("s_waitcnt vmcnt(8)" ::: "memory");
    __builtin_amdgcn_s_barrier();
    __builtin_amdgcn_sched_barrier(0);
    compute(cur, k0);
    __builtin_amdgcn_s_barrier();
    cur ^= 1;
  }
  asm volatile("s_waitcnt vmcnt(0)" ::: "memory");
  __builtin_amdgcn_s_barrier();
  __builtin_amdgcn_sched_barrier(0);
  compute(cur, kend - 32);

  f32x4 linv;
#pragma unroll
  for (int jj = 0; jj < 4; ++jj) linv[jj] = 1.0f / __shfl(lrun, l4 * 4 + jj);
#pragma unroll
  for (int jj = 0; jj < 4; ++jj) {
    int row = s0 + w * 16 + l4 * 4 + jj;
    U16* op = O + ((long)b * 2048 + row) * 4096 + h * 256 + l15;
#pragma unroll
    for (int n = 0; n < 16; ++n) op[n * 16] = f2bf(acc[n][jj] * linv[jj]);
  }
}

// ----------------------------------------------------------------------------
extern "C" void kernel_launch(void* const* d_in, const int* in_sizes, int n_in,
                              void* d_out, int out_size, void* d_ws, size_t ws_size,
                              hipStream_t stream) {
  if (n_in < 5) return;
  const float* hid = (const float*)d_in[0];
  const float* Wq  = (const float*)d_in[1];
  const float* Wk  = (const float*)d_in[2];
  const float* Wv  = (const float*)d_in[3];
  const float* Wo  = (const float*)d_in[4];

  char* ws = (char*)d_ws;
  size_t off = 0;
  auto alloc = [&](size_t bytes) {
    char* p = ws + off;
    off += (bytes + 255) & ~(size_t)255;
    return p;
  };
  float* cosT = (float*)alloc((size_t)2048 * 128 * 4);
  float* sinT = (float*)alloc((size_t)2048 * 128 * 4);
  U16*   Xb   = (U16*)alloc((size_t)4096 * 3584 * 2);   // reused: VT, then Wot
  U16*   Wt   = (U16*)alloc((size_t)8192 * 3584 * 2);   // reused: AttO
  U16*   QKV  = (U16*)alloc((size_t)4096 * 8192 * 2);
  if (off > ws_size) return;
  U16* VT   = Xb;
  U16* Wot  = Xb;
  U16* AttO = Wt;

  k_convert<<<7168, 256, 0, stream>>>(hid, Xb, (long)4096 * 3584);
  k_transpose<<<dim3(128, 112), 256, 0, stream>>>(Wq, Wt, 3584, 4096);
  k_transpose<<<dim3(64, 112), 256, 0, stream>>>(Wk, Wt + (size_t)4096 * 3584, 3584, 2048);
  k_transpose<<<dim3(64, 112), 256, 0, stream>>>(Wv, Wt + (size_t)6144 * 3584, 3584, 2048);
  k_rope_tables<<<1024, 256, 0, stream>>>(cosT, sinT);
  k_gemm8<0><<<dim3(32, 16), 512, 0, stream>>>(Xb, Wt, QKV, 4096, 8192, 3584);
  k_vtrans<<<dim3(64, 8, 16), 256, 0, stream>>>(QKV, VT);
  k_rope<<<49152, 256, 0, stream>>>(QKV, cosT, sinT);
  k_attn<<<dim3(32, 16, 2), 256, 0, stream>>>(QKV, VT, AttO);
  k_transpose<<<dim3(112, 128), 256, 0, stream>>>(Wo, Wot, 4096, 3584);
  k_gemm8<1><<<dim3(14, 16), 512, 0, stream>>>(AttO, Wot, d_out, 4096, 3584, 4096);
}

// Round 12
// 688.773 us; speedup vs baseline: 1.1469x; 1.0177x over previous
//
#include <hip/hip_runtime.h>
#include <stdint.h>

typedef unsigned short U16;
typedef float f32x4 __attribute__((ext_vector_type(4)));
typedef __bf16 bf16x8 __attribute__((ext_vector_type(8)));

static __device__ __forceinline__ U16 f2bf(float x) {
  union { float f; unsigned u; } v; v.f = x;
  unsigned r = v.u + 0x7FFFu + ((v.u >> 16) & 1u);
  return (U16)(r >> 16);
}
static __device__ __forceinline__ float bf2f(U16 h) {
  union { unsigned u; float f; } v; v.u = ((unsigned)h) << 16;
  return v.f;
}

static __device__ __forceinline__ void gload_lds16(const void* g, void* l) {
  __builtin_amdgcn_global_load_lds(
      (const __attribute__((address_space(1))) void*)g,
      (__attribute__((address_space(3))) void*)l, 16, 0, 0);
}

#define SBAR() __builtin_amdgcn_sched_barrier(0)

// ---------------- hidden (fp32) -> bf16 -------------------------------------
__global__ __launch_bounds__(256) void k_convert(const float* __restrict__ src,
                                                 U16* __restrict__ dst, long n) {
  long base = ((long)blockIdx.x * 256 + threadIdx.x) * 8;
  if (base >= n) return;
  const float4* s = (const float4*)(src + base);
  float4 a = s[0], b = s[1];
  U16 o[8] = { f2bf(a.x), f2bf(a.y), f2bf(a.z), f2bf(a.w),
               f2bf(b.x), f2bf(b.y), f2bf(b.z), f2bf(b.w) };
  *(uint4*)(dst + base) = *(const uint4*)o;
}

// ---------------- W[K][N] (fp32) -> Wt[N][K] bf16 ----------------------------
__global__ __launch_bounds__(256) void k_transpose(const float* __restrict__ src,
                                                   U16* __restrict__ dst,
                                                   int K, int N) {
  __shared__ U16 tile[32][33];
  int n0 = blockIdx.x * 32, k0 = blockIdx.y * 32;
  int tx = threadIdx.x & 31, ty = threadIdx.x >> 5;
#pragma unroll
  for (int r = 0; r < 4; ++r) {
    int k = k0 + ty + r * 8;
    tile[ty + r * 8][tx] = f2bf(src[(long)k * N + n0 + tx]);
  }
  __syncthreads();
#pragma unroll
  for (int r = 0; r < 4; ++r) {
    int n = n0 + ty + r * 8;
    dst[(long)n * K + k0 + tx] = tile[tx][ty + r * 8];
  }
}

// ---- V section of QKV -> VT tiled [bk][sTile=64][d=256][s32=32] bf16 -------
__global__ __launch_bounds__(256) void k_vtrans(const U16* __restrict__ QKV,
                                                U16* __restrict__ VT) {
  __shared__ U16 tile[32][33];
  int s0 = blockIdx.x * 32, d0 = blockIdx.y * 32, bk = blockIdx.z;
  int b = bk >> 3, kvh = bk & 7;
  int tx = threadIdx.x & 31, ty = threadIdx.x >> 5;
  const U16* src = QKV + (long)(b * 2048) * 8192 + 6144 + kvh * 256;
#pragma unroll
  for (int r = 0; r < 4; ++r) {
    int s = s0 + ty + r * 8;
    tile[ty + r * 8][tx] = src[(long)s * 8192 + d0 + tx];
  }
  __syncthreads();
  long tbase = ((long)bk * 64 + (s0 >> 5)) * 8192;
#pragma unroll
  for (int r = 0; r < 4; ++r) {
    int d = d0 + ty + r * 8;
    VT[tbase + d * 32 + tx] = tile[tx][ty + r * 8];
  }
}

// ---------------- RoPE tables (fp32) ----------------------------------------
__global__ __launch_bounds__(256) void k_rope_tables(float* __restrict__ cosT,
                                                     float* __restrict__ sinT) {
  int i = blockIdx.x * 256 + threadIdx.x;
  int s = i >> 7, d = i & 127;
  float freq = expf(-9.210340371976184f * (float)d / 128.0f);
  float ang = (float)s * freq;
  cosT[i] = cosf(ang);
  sinT[i] = sinf(ang);
}

// ---------------- RoPE in place on q,k sections of QKV ----------------------
__global__ __launch_bounds__(256) void k_rope(U16* __restrict__ qkv,
                                              const float* __restrict__ cosT,
                                              const float* __restrict__ sinT) {
  int i = blockIdx.x * 256 + threadIdx.x;
  int d = i & 127;
  int hh = (i >> 7) % 24;
  int row = i / 3072;
  int s = row & 2047;
  int col = (hh < 16) ? hh * 256 + d : 4096 + (hh - 16) * 256 + d;
  long base = (long)row * 8192 + col;
  float c = cosT[s * 128 + d], sn = sinT[s * 128 + d];
  float x1 = bf2f(qkv[base]), x2 = bf2f(qkv[base + 128]);
  qkv[base]       = f2bf(x1 * c - x2 * sn);
  qkv[base + 128] = f2bf(x2 * c + x1 * sn);
}

// ---------------- GEMM v5: 256x256, BK=64, 8 waves, 8-PHASE (unchanged) -----
template <int F32OUT>
__global__ __launch_bounds__(512, 1) void k_gemm8(const U16* __restrict__ A,
                                                  const U16* __restrict__ Bt,
                                                  void* __restrict__ Cv,
                                                  int M, int N, int K) {
  __shared__ __align__(16) U16 Asl[2][2][128 * 64];
  __shared__ __align__(16) U16 Bsl[2][2][128 * 64];
  int nwg = gridDim.x * gridDim.y;
  int flat = blockIdx.y * gridDim.x + blockIdx.x;
  int cpx = nwg >> 3;
  int swz = (flat & 7) * cpx + (flat >> 3);
  int bx = swz % gridDim.x, by = swz / gridDim.x;
  int t = threadIdx.x, lane = t & 63, w = t >> 6;
  int m0 = by * 256, n0 = bx * 256;
  int wm = w >> 2, wn = w & 3;
  int l15 = lane & 15, l4 = lane >> 4;
  int lofs = (l15 * 4 + l4) * 16;

  f32x4 acc[8][4] = {};
  int T = K >> 6;

  int sr = lane >> 2, sc4 = (lane & 3) * 8;
  int fA0 = (w >> 1) * 16 + sr, kA0 = (w & 1) * 32 + sc4;
  int fA1 = ((8 + w) >> 1) * 16 + sr, kA1 = ((8 + w) & 1) * 32 + sc4;
  const U16* aj0 = A + (long)(m0 + fA0) * K + kA0;
  const U16* aj1 = A + (long)(m0 + fA1) * K + kA1;
  const U16* bj0 = Bt + (long)(n0 + fA0) * K + kA0;
  const U16* bj1 = Bt + (long)(n0 + fA1) * K + kA1;

  auto stageH = [&](int op, int kt, int h) {
    int buf = kt & 1;
    int ktc = (kt < T) ? kt : 0;
    long off = (long)ktc * 64 + (long)h * 128 * K;
    if (op == 0) {
      gload_lds16(aj0 + off, (char*)&Asl[buf][h][0] + w * 1024);
      gload_lds16(aj1 + off, (char*)&Asl[buf][h][0] + 8192 + w * 1024);
    } else {
      gload_lds16(bj0 + off, (char*)&Bsl[buf][h][0] + w * 1024);
      gload_lds16(bj1 + off, (char*)&Bsl[buf][h][0] + 8192 + w * 1024);
    }
  };

  bf16x8 Ar[4][2], Bq[2][2][2];

  auto readA = [&](int buf, int r) {
    const char* base = (const char*)&Asl[buf][wm][0] + lofs;
#pragma unroll
    for (int i = 0; i < 4; ++i)
#pragma unroll
      for (int kk = 0; kk < 2; ++kk)
        Ar[i][kk] = *(const bf16x8*)(base + ((r * 4 + i) * 2 + kk) * 1024);
  };
  auto readB = [&](int buf, int c) {
    const char* base = (const char*)&Bsl[buf][wn >> 1][0] + lofs;
#pragma unroll
    for (int j = 0; j < 2; ++j)
#pragma unroll
      for (int kk = 0; kk < 2; ++kk)
        Bq[c][j][kk] = *(const bf16x8*)(base + (((wn & 1) * 4 + c * 2 + j) * 2 + kk) * 1024);
  };
  auto mfmaQ = [&](int r, int c) {
    __builtin_amdgcn_s_setprio(1);
#pragma unroll
    for (int i = 0; i < 4; ++i)
#pragma unroll
      for (int j = 0; j < 2; ++j) {
        int m = r * 4 + i, n = c * 2 + j;
        acc[m][n] = __builtin_amdgcn_mfma_f32_16x16x32_bf16(Ar[i][0], Bq[c][j][0], acc[m][n], 0, 0, 0);
        acc[m][n] = __builtin_amdgcn_mfma_f32_16x16x32_bf16(Ar[i][1], Bq[c][j][1], acc[m][n], 0, 0, 0);
      }
    __builtin_amdgcn_s_setprio(0);
  };

#define PH_SYNC() do { SBAR(); __builtin_amdgcn_s_barrier(); \
    asm volatile("s_waitcnt lgkmcnt(0)" ::: "memory"); SBAR(); } while (0)
#define PH_END() do { SBAR(); __builtin_amdgcn_s_barrier(); SBAR(); } while (0)

  stageH(0, 0, 0); stageH(0, 0, 1); stageH(1, 0, 0); stageH(1, 0, 1);
  stageH(1, 1, 0); stageH(0, 1, 0);
  asm volatile("s_waitcnt vmcnt(4)" ::: "memory");
  SBAR(); __builtin_amdgcn_s_barrier(); SBAR();

  for (int base = 0; base < T; base += 2) {
    readA(0, 0); readB(0, 0);
    stageH(0, base + 1, 1);
    PH_SYNC(); mfmaQ(0, 0); PH_END();
    readB(0, 1);
    stageH(1, base + 1, 1);
    PH_SYNC(); mfmaQ(0, 1); PH_END();
    readA(0, 1);
    stageH(1, base + 2, 0);
    PH_SYNC(); mfmaQ(1, 1); PH_END();
    stageH(0, base + 2, 0);
    PH_SYNC(); mfmaQ(1, 0);
    asm volatile("s_waitcnt vmcnt(4)" ::: "memory");
    PH_END();
    readA(1, 0); readB(1, 0);
    stageH(0, base + 2, 1);
    PH_SYNC(); mfmaQ(0, 0); PH_END();
    readB(1, 1);
    stageH(1, base + 2, 1);
    PH_SYNC(); mfmaQ(0, 1); PH_END();
    readA(1, 1);
    stageH(1, base + 3, 0);
    PH_SYNC(); mfmaQ(1, 1); PH_END();
    stageH(0, base + 3, 0);
    PH_SYNC(); mfmaQ(1, 0);
    asm volatile("s_waitcnt vmcnt(4)" ::: "memory");
    PH_END();
  }

#undef PH_SYNC
#undef PH_END

#pragma unroll
  for (int m = 0; m < 8; ++m)
#pragma unroll
    for (int jj = 0; jj < 4; ++jj) {
      int row = m0 + wm * 128 + m * 16 + l4 * 4 + jj;
      if (F32OUT) {
        float* cp = (float*)Cv + (long)row * N + n0 + wn * 64 + l15;
#pragma unroll
        for (int n = 0; n < 4; ++n) cp[n * 16] = acc[m][n][jj];
      } else {
        U16* cp = (U16*)Cv + (long)row * N + n0 + wn * 64 + l15;
#pragma unroll
        for (int n = 0; n < 4; ++n) cp[n * 16] = f2bf(acc[m][n][jj]);
      }
    }
}

// ---------------- banded GQA attention (v6: fragment-linear, lean VALU) -----
// K granule f=mp*8+kc at f*1024+(l15*4+l4)*16 holds K[mp*16+l15][kc*32+l4*8..+7].
// V granule n at n*1024+(l15*4+l4)*16 holds VT[n*16+l15][l4*8..+7].
// Staging source encodes the permutation; dest stays uniform-base + lane*16.
// Compute reads are base + const*1024 (zero VALU, conflict-free).
__global__ __launch_bounds__(256) void k_attn(const U16* __restrict__ QKV,
                                              const U16* __restrict__ VT,
                                              U16* __restrict__ O) {
  __shared__ __align__(16) U16 Ks[2][32 * 256];
  __shared__ __align__(16) U16 Vs[2][256 * 32];
  __shared__ __align__(16) U16 Plds[4][16 * 40];
  int t = threadIdx.x, lane = t & 63, w = t >> 6;
  int flat = blockIdx.x + 32 * (blockIdx.y + 16 * blockIdx.z);
  int l = (flat & 7) * 128 + (flat >> 3);
  int qb = l & 31, h = (l >> 5) & 15, b = l >> 9;
  int s0 = qb * 64;
  int kvh = h >> 1;
  long rowOff = (long)b * 2048 * 8192;
  const U16* Qb = QKV + rowOff + h * 256;
  const U16* Kb = QKV + rowOff + 4096 + kvh * 256;
  const U16* VTb = VT + (long)(b * 8 + kvh) * 64 * 8192;

  int l15 = lane & 15, l4 = lane >> 4;
  int lofs = (l15 * 4 + l4) * 16;

  bf16x8 qf[8];
  {
    const U16* qp = Qb + (long)(s0 + w * 16 + l15) * 8192 + l4 * 8;
#pragma unroll
    for (int kc = 0; kc < 8; ++kc) qf[kc] = *(const bf16x8*)(qp + kc * 32);
  }
  asm volatile("s_waitcnt vmcnt(0)" ::: "memory");

  f32x4 acc[16] = {};
  float mrun = -1e30f, lrun = 0.0f;
  int qpos = s0 + w * 16 + l15;
  int qlo = s0 + w * 16, qhi = qlo + 15;

  int kstart = s0 - 1024; if (kstart < 0) kstart = 0;
  int kend = s0 + 64 + 1024; if (kend > 2048) kend = 2048;

  // fragment-linear staging source offsets (int: < 2^19 elements)
  int sl15 = (t >> 2) & 15, sl4 = t & 3;
  int offK[4], offV[4];
#pragma unroll
  for (int i = 0; i < 4; ++i) {
    int f = i * 4 + w;
    offK[i] = ((f >> 3) * 16 + sl15) * 8192 + (f & 7) * 32 + sl4 * 8;
    offV[i] = (f * 16 + sl15) * 32 + sl4 * 8;
  }

  const U16* kb = Kb + (long)kstart * 8192;
  const U16* vt0 = VTb + (long)(kstart >> 5) * 8192;

  auto stage = [&](int buf) {
#pragma unroll
    for (int i = 0; i < 4; ++i)
      gload_lds16(kb + offK[i], (char*)&Ks[buf][0] + i * 4096 + w * 1024);
#pragma unroll
    for (int i = 0; i < 4; ++i)
      gload_lds16(vt0 + offV[i], (char*)&Vs[buf][0] + i * 4096 + w * 1024);
    kb += (long)32 * 8192;
    vt0 += 8192;
  };

  auto compute = [&](int buf, int k0) {
    f32x4 sAcc[2] = {};
    const char* Kc = (const char*)&Ks[buf][0] + lofs;
    __builtin_amdgcn_s_setprio(1);
#pragma unroll
    for (int kc = 0; kc < 8; ++kc) {
      bf16x8 a0 = *(const bf16x8*)(Kc + kc * 1024);
      bf16x8 a1 = *(const bf16x8*)(Kc + (8 + kc) * 1024);
      sAcc[0] = __builtin_amdgcn_mfma_f32_16x16x32_bf16(a0, qf[kc], sAcc[0], 0, 0, 0);
      sAcc[1] = __builtin_amdgcn_mfma_f32_16x16x32_bf16(a1, qf[kc], sAcc[1], 0, 0, 0);
    }
    __builtin_amdgcn_s_setprio(0);
    // softcap: 50*tanh(s*0.00125) = 50 - 100/(exp(s*0.0025)+1)
    float sv[8];
#pragma unroll
    for (int mp = 0; mp < 2; ++mp)
#pragma unroll
      for (int jj = 0; jj < 4; ++jj) {
        float ex = __expf(sAcc[mp][jj] * 0.0025f);
        sv[mp * 4 + jj] = fmaf(-100.0f, __builtin_amdgcn_rcpf(ex + 1.0f), 50.0f);
      }
    // band mask only on boundary tiles (wave-uniform branch)
    bool full = ((qhi - k0) <= 1024) && ((k0 + 31 - qlo) <= 1024);
    if (!full) {
#pragma unroll
      for (int mp = 0; mp < 2; ++mp)
#pragma unroll
        for (int jj = 0; jj < 4; ++jj) {
          int key = k0 + mp * 16 + l4 * 4 + jj;
          int dd = qpos - key;
          if (dd < -1024 || dd > 1024) sv[mp * 4 + jj] = -3e38f;
        }
    }
    float tmax = sv[0];
#pragma unroll
    for (int i = 1; i < 8; ++i) tmax = fmaxf(tmax, sv[i]);
    tmax = fmaxf(tmax, __shfl_xor(tmax, 16));
    tmax = fmaxf(tmax, __shfl_xor(tmax, 32));
    bool skipall = __all((tmax <= mrun + 8.0f) ? 1 : 0) != 0;
    float mnew = skipall ? mrun : fmaxf(mrun, tmax);
    float pex[8];
    float psum = 0.0f;
#pragma unroll
    for (int i = 0; i < 8; ++i) { pex[i] = __expf(sv[i] - mnew); psum += pex[i]; }
    psum += __shfl_xor(psum, 16);
    psum += __shfl_xor(psum, 32);
    if (skipall) {
      lrun += psum;
    } else {
      float esc = __expf(mrun - mnew);
      f32x4 ev;
#pragma unroll
      for (int jj = 0; jj < 4; ++jj) ev[jj] = __shfl(esc, l4 * 4 + jj);
#pragma unroll
      for (int n = 0; n < 16; ++n) acc[n] *= ev;
      lrun = lrun * esc + psum;
      mrun = mnew;
    }
#pragma unroll
    for (int mp = 0; mp < 2; ++mp)
#pragma unroll
      for (int j2 = 0; j2 < 2; ++j2) {
        unsigned lo = f2bf(pex[mp * 4 + j2 * 2]);
        unsigned hi = f2bf(pex[mp * 4 + j2 * 2 + 1]);
        *(unsigned*)&Plds[w][l15 * 40 + mp * 16 + l4 * 4 + j2 * 2] = lo | (hi << 16);
      }
    asm volatile("s_waitcnt lgkmcnt(0)" ::: "memory");
    __builtin_amdgcn_sched_barrier(0);
    bf16x8 pa = *(const bf16x8*)&Plds[w][l15 * 40 + l4 * 8];
    const char* Vc = (const char*)&Vs[buf][0] + lofs;
    __builtin_amdgcn_s_setprio(1);
#pragma unroll
    for (int n = 0; n < 16; ++n) {
      bf16x8 vb = *(const bf16x8*)(Vc + n * 1024);
      acc[n] = __builtin_amdgcn_mfma_f32_16x16x32_bf16(pa, vb, acc[n], 0, 0, 0);
    }
    __builtin_amdgcn_s_setprio(0);
  };

  int cur = 0;
  stage(0);
  for (int k0 = kstart; k0 < kend - 32; k0 += 32) {
    stage(cur ^ 1);
    asm volatile("s_waitcnt vmcnt(8)" ::: "memory");
    __builtin_amdgcn_s_barrier();
    __builtin_amdgcn_sched_barrier(0);
    compute(cur, k0);
    __builtin_amdgcn_s_barrier();
    cur ^= 1;
  }
  asm volatile("s_waitcnt vmcnt(0)" ::: "memory");
  __builtin_amdgcn_s_barrier();
  __builtin_amdgcn_sched_barrier(0);
  compute(cur, kend - 32);

  f32x4 linv;
#pragma unroll
  for (int jj = 0; jj < 4; ++jj) linv[jj] = 1.0f / __shfl(lrun, l4 * 4 + jj);
#pragma unroll
  for (int jj = 0; jj < 4; ++jj) {
    int row = s0 + w * 16 + l4 * 4 + jj;
    U16* op = O + ((long)b * 2048 + row) * 4096 + h * 256 + l15;
#pragma unroll
    for (int n = 0; n < 16; ++n) op[n * 16] = f2bf(acc[n][jj] * linv[jj]);
  }
}

// ----------------------------------------------------------------------------
extern "C" void kernel_launch(void* const* d_in, const int* in_sizes, int n_in,
                              void* d_out, int out_size, void* d_ws, size_t ws_size,
                              hipStream_t stream) {
  if (n_in < 5) return;
  const float* hid = (const float*)d_in[0];
  const float* Wq  = (const float*)d_in[1];
  const float* Wk  = (const float*)d_in[2];
  const float* Wv  = (const float*)d_in[3];
  const float* Wo  = (const float*)d_in[4];

  char* ws = (char*)d_ws;
  size_t off = 0;
  auto alloc = [&](size_t bytes) {
    char* p = ws + off;
    off += (bytes + 255) & ~(size_t)255;
    return p;
  };
  float* cosT = (float*)alloc((size_t)2048 * 128 * 4);
  float* sinT = (float*)alloc((size_t)2048 * 128 * 4);
  U16*   Xb   = (U16*)alloc((size_t)4096 * 3584 * 2);   // reused: VT, then Wot
  U16*   Wt   = (U16*)alloc((size_t)8192 * 3584 * 2);   // reused: AttO
  U16*   QKV  = (U16*)alloc((size_t)4096 * 8192 * 2);
  if (off > ws_size) return;
  U16* VT   = Xb;
  U16* Wot  = Xb;
  U16* AttO = Wt;

  k_convert<<<7168, 256, 0, stream>>>(hid, Xb, (long)4096 * 3584);
  k_transpose<<<dim3(128, 112), 256, 0, stream>>>(Wq, Wt, 3584, 4096);
  k_transpose<<<dim3(64, 112), 256, 0, stream>>>(Wk, Wt + (size_t)4096 * 3584, 3584, 2048);
  k_transpose<<<dim3(64, 112), 256, 0, stream>>>(Wv, Wt + (size_t)6144 * 3584, 3584, 2048);
  k_rope_tables<<<1024, 256, 0, stream>>>(cosT, sinT);
  k_gemm8<0><<<dim3(32, 16), 512, 0, stream>>>(Xb, Wt, QKV, 4096, 8192, 3584);
  k_vtrans<<<dim3(64, 8, 16), 256, 0, stream>>>(QKV, VT);
  k_rope<<<49152, 256, 0, stream>>>(QKV, cosT, sinT);
  k_attn<<<dim3(32, 16, 2), 256, 0, stream>>>(QKV, VT, AttO);
  k_transpose<<<dim3(112, 128), 256, 0, stream>>>(Wo, Wot, 4096, 3584);
  k_gemm8<1><<<dim3(14, 16), 512, 0, stream>>>(AttO, Wot, d_out, 4096, 3584, 4096);
}

// Round 13
// 676.950 us; speedup vs baseline: 1.1669x; 1.0175x over previous
//
#include <hip/hip_runtime.h>
#include <stdint.h>

typedef unsigned short U16;
typedef float f32x4 __attribute__((ext_vector_type(4)));
typedef __bf16 bf16x8 __attribute__((ext_vector_type(8)));

static __device__ __forceinline__ U16 f2bf(float x) {
  union { float f; unsigned u; } v; v.f = x;
  unsigned r = v.u + 0x7FFFu + ((v.u >> 16) & 1u);
  return (U16)(r >> 16);
}
static __device__ __forceinline__ float bf2f(U16 h) {
  union { unsigned u; float f; } v; v.u = ((unsigned)h) << 16;
  return v.f;
}

static __device__ __forceinline__ void gload_lds16(const void* g, void* l) {
  __builtin_amdgcn_global_load_lds(
      (const __attribute__((address_space(1))) void*)g,
      (__attribute__((address_space(3))) void*)l, 16, 0, 0);
}

#define SBAR() __builtin_amdgcn_sched_barrier(0)

// ---------------- hidden (fp32) -> bf16 -------------------------------------
__global__ __launch_bounds__(256) void k_convert(const float* __restrict__ src,
                                                 U16* __restrict__ dst, long n) {
  long base = ((long)blockIdx.x * 256 + threadIdx.x) * 8;
  if (base >= n) return;
  const float4* s = (const float4*)(src + base);
  float4 a = s[0], b = s[1];
  U16 o[8] = { f2bf(a.x), f2bf(a.y), f2bf(a.z), f2bf(a.w),
               f2bf(b.x), f2bf(b.y), f2bf(b.z), f2bf(b.w) };
  *(uint4*)(dst + base) = *(const uint4*)o;
}

// ---------------- W[K][N] (fp32) -> Wt[N][K] bf16 ----------------------------
__global__ __launch_bounds__(256) void k_transpose(const float* __restrict__ src,
                                                   U16* __restrict__ dst,
                                                   int K, int N) {
  __shared__ U16 tile[32][33];
  int n0 = blockIdx.x * 32, k0 = blockIdx.y * 32;
  int tx = threadIdx.x & 31, ty = threadIdx.x >> 5;
#pragma unroll
  for (int r = 0; r < 4; ++r) {
    int k = k0 + ty + r * 8;
    tile[ty + r * 8][tx] = f2bf(src[(long)k * N + n0 + tx]);
  }
  __syncthreads();
#pragma unroll
  for (int r = 0; r < 4; ++r) {
    int n = n0 + ty + r * 8;
    dst[(long)n * K + k0 + tx] = tile[tx][ty + r * 8];
  }
}

// ---- V section of QKV -> VT tiled [bk][sTile=64][d=256][s32=32] bf16 -------
__global__ __launch_bounds__(256) void k_vtrans(const U16* __restrict__ QKV,
                                                U16* __restrict__ VT) {
  __shared__ U16 tile[32][33];
  int s0 = blockIdx.x * 32, d0 = blockIdx.y * 32, bk = blockIdx.z;
  int b = bk >> 3, kvh = bk & 7;
  int tx = threadIdx.x & 31, ty = threadIdx.x >> 5;
  const U16* src = QKV + (long)(b * 2048) * 8192 + 6144 + kvh * 256;
#pragma unroll
  for (int r = 0; r < 4; ++r) {
    int s = s0 + ty + r * 8;
    tile[ty + r * 8][tx] = src[(long)s * 8192 + d0 + tx];
  }
  __syncthreads();
  long tbase = ((long)bk * 64 + (s0 >> 5)) * 8192;
#pragma unroll
  for (int r = 0; r < 4; ++r) {
    int d = d0 + ty + r * 8;
    VT[tbase + d * 32 + tx] = tile[tx][ty + r * 8];
  }
}

// ---------------- RoPE tables (fp32) ----------------------------------------
__global__ __launch_bounds__(256) void k_rope_tables(float* __restrict__ cosT,
                                                     float* __restrict__ sinT) {
  int i = blockIdx.x * 256 + threadIdx.x;
  int s = i >> 7, d = i & 127;
  float freq = expf(-9.210340371976184f * (float)d / 128.0f);
  float ang = (float)s * freq;
  cosT[i] = cosf(ang);
  sinT[i] = sinf(ang);
}

// ---------------- GEMM v6: 256x256, BK=64, 8 waves, 8-PHASE + fused rope ----
// Wave->column remap: wave wn owns two 32-col strips 128 apart:
//   col(n) = c*128 + wn*32 + j*16 + l15  (n = c*2+j)
// -> a RoPE pair (d, d+128) is (acc[m][j], acc[m][2+j]) in ONE thread.
// EPI=0: bf16 out with rope on Q/K blocks (n0<6144), plain on V blocks.
// EPI=1: fp32 out, plain. Per-C-element K-order unchanged.
template <int EPI>
__global__ __launch_bounds__(512, 1) void k_gemm8(const U16* __restrict__ A,
                                                  const U16* __restrict__ Bt,
                                                  void* __restrict__ Cv,
                                                  const float* __restrict__ cosT,
                                                  const float* __restrict__ sinT,
                                                  int M, int N, int K) {
  __shared__ __align__(16) U16 Asl[2][2][128 * 64];
  __shared__ __align__(16) U16 Bsl[2][2][128 * 64];
  int nwg = gridDim.x * gridDim.y;
  int flat = blockIdx.y * gridDim.x + blockIdx.x;
  int cpx = nwg >> 3;
  int swz = (flat & 7) * cpx + (flat >> 3);
  int bx = swz % gridDim.x, by = swz / gridDim.x;
  int t = threadIdx.x, lane = t & 63, w = t >> 6;
  int m0 = by * 256, n0 = bx * 256;
  int wm = w >> 2, wn = w & 3;
  int l15 = lane & 15, l4 = lane >> 4;
  int lofs = (l15 * 4 + l4) * 16;

  f32x4 acc[8][4] = {};
  int T = K >> 6;

  int sr = lane >> 2, sc4 = (lane & 3) * 8;
  int fA0 = (w >> 1) * 16 + sr, kA0 = (w & 1) * 32 + sc4;
  int fA1 = ((8 + w) >> 1) * 16 + sr, kA1 = ((8 + w) & 1) * 32 + sc4;
  const U16* aj0 = A + (long)(m0 + fA0) * K + kA0;
  const U16* aj1 = A + (long)(m0 + fA1) * K + kA1;
  const U16* bj0 = Bt + (long)(n0 + fA0) * K + kA0;
  const U16* bj1 = Bt + (long)(n0 + fA1) * K + kA1;

  auto stageH = [&](int op, int kt, int h) {
    int buf = kt & 1;
    int ktc = (kt < T) ? kt : 0;
    long off = (long)ktc * 64 + (long)h * 128 * K;
    if (op == 0) {
      gload_lds16(aj0 + off, (char*)&Asl[buf][h][0] + w * 1024);
      gload_lds16(aj1 + off, (char*)&Asl[buf][h][0] + 8192 + w * 1024);
    } else {
      gload_lds16(bj0 + off, (char*)&Bsl[buf][h][0] + w * 1024);
      gload_lds16(bj1 + off, (char*)&Bsl[buf][h][0] + 8192 + w * 1024);
    }
  };

  bf16x8 Ar[4][2], Bq[2][2][2];

  auto readA = [&](int buf, int r) {
    const char* base = (const char*)&Asl[buf][wm][0] + lofs;
#pragma unroll
    for (int i = 0; i < 4; ++i)
#pragma unroll
      for (int kk = 0; kk < 2; ++kk)
        Ar[i][kk] = *(const bf16x8*)(base + ((r * 4 + i) * 2 + kk) * 1024);
  };
  // c selects the 128-offset column strip: half = c, sub-blocks 2wn, 2wn+1
  auto readB = [&](int buf, int c) {
    const char* base = (const char*)&Bsl[buf][c][0] + lofs;
#pragma unroll
    for (int j = 0; j < 2; ++j)
#pragma unroll
      for (int kk = 0; kk < 2; ++kk)
        Bq[c][j][kk] = *(const bf16x8*)(base + ((2 * wn + j) * 2 + kk) * 1024);
  };
  auto mfmaQ = [&](int r, int c) {
    __builtin_amdgcn_s_setprio(1);
#pragma unroll
    for (int i = 0; i < 4; ++i)
#pragma unroll
      for (int j = 0; j < 2; ++j) {
        int m = r * 4 + i, n = c * 2 + j;
        acc[m][n] = __builtin_amdgcn_mfma_f32_16x16x32_bf16(Ar[i][0], Bq[c][j][0], acc[m][n], 0, 0, 0);
        acc[m][n] = __builtin_amdgcn_mfma_f32_16x16x32_bf16(Ar[i][1], Bq[c][j][1], acc[m][n], 0, 0, 0);
      }
    __builtin_amdgcn_s_setprio(0);
  };

#define PH_SYNC() do { SBAR(); __builtin_amdgcn_s_barrier(); \
    asm volatile("s_waitcnt lgkmcnt(0)" ::: "memory"); SBAR(); } while (0)
#define PH_END() do { SBAR(); __builtin_amdgcn_s_barrier(); SBAR(); } while (0)

  stageH(0, 0, 0); stageH(0, 0, 1); stageH(1, 0, 0); stageH(1, 0, 1);
  stageH(1, 1, 0); stageH(0, 1, 0);
  asm volatile("s_waitcnt vmcnt(4)" ::: "memory");
  SBAR(); __builtin_amdgcn_s_barrier(); SBAR();

  for (int base = 0; base < T; base += 2) {
    readA(0, 0); readB(0, 0);
    stageH(0, base + 1, 1);
    PH_SYNC(); mfmaQ(0, 0); PH_END();
    readB(0, 1);
    stageH(1, base + 1, 1);
    PH_SYNC(); mfmaQ(0, 1); PH_END();
    readA(0, 1);
    stageH(1, base + 2, 0);
    PH_SYNC(); mfmaQ(1, 1); PH_END();
    stageH(0, base + 2, 0);
    PH_SYNC(); mfmaQ(1, 0);
    asm volatile("s_waitcnt vmcnt(4)" ::: "memory");
    PH_END();
    readA(1, 0); readB(1, 0);
    stageH(0, base + 2, 1);
    PH_SYNC(); mfmaQ(0, 0); PH_END();
    readB(1, 1);
    stageH(1, base + 2, 1);
    PH_SYNC(); mfmaQ(0, 1); PH_END();
    readA(1, 1);
    stageH(1, base + 3, 0);
    PH_SYNC(); mfmaQ(1, 1); PH_END();
    stageH(0, base + 3, 0);
    PH_SYNC(); mfmaQ(1, 0);
    asm volatile("s_waitcnt vmcnt(4)" ::: "memory");
    PH_END();
  }

#undef PH_SYNC
#undef PH_END

  // epilogue with remapped columns: col(n=c*2+j) = n0 + c*128 + wn*32 + j*16 + l15
  bool doRope = (EPI == 0) && (n0 < 6144);
#pragma unroll
  for (int m = 0; m < 8; ++m)
#pragma unroll
    for (int jj = 0; jj < 4; ++jj) {
      int row = m0 + wm * 128 + m * 16 + l4 * 4 + jj;
      int s2 = row & 2047;
#pragma unroll
      for (int j = 0; j < 2; ++j) {
        float lo = acc[m][j][jj];
        float hi = acc[m][2 + j][jj];
        int cl = wn * 32 + j * 16 + l15;
        if (EPI == 0) {
          if (doRope) {
            int d = cl;                       // cl < 128 always
            float co = cosT[s2 * 128 + d];
            float si = sinT[s2 * 128 + d];
            float o0 = lo * co - hi * si;
            float o1 = hi * co + lo * si;
            lo = o0; hi = o1;
          }
          U16* cp = (U16*)Cv + (long)row * N + n0 + cl;
          cp[0] = f2bf(lo);
          cp[128] = f2bf(hi);
        } else {
          float* cp = (float*)Cv + (long)row * N + n0 + cl;
          cp[0] = lo;
          cp[128] = hi;
        }
      }
    }
}

// ---------------- banded GQA attention (v6, unchanged) ----------------------
__global__ __launch_bounds__(256) void k_attn(const U16* __restrict__ QKV,
                                              const U16* __restrict__ VT,
                                              U16* __restrict__ O) {
  __shared__ __align__(16) U16 Ks[2][32 * 256];
  __shared__ __align__(16) U16 Vs[2][256 * 32];
  __shared__ __align__(16) U16 Plds[4][16 * 40];
  int t = threadIdx.x, lane = t & 63, w = t >> 6;
  int flat = blockIdx.x + 32 * (blockIdx.y + 16 * blockIdx.z);
  int l = (flat & 7) * 128 + (flat >> 3);
  int qb = l & 31, h = (l >> 5) & 15, b = l >> 9;
  int s0 = qb * 64;
  int kvh = h >> 1;
  long rowOff = (long)b * 2048 * 8192;
  const U16* Qb = QKV + rowOff + h * 256;
  const U16* Kb = QKV + rowOff + 4096 + kvh * 256;
  const U16* VTb = VT + (long)(b * 8 + kvh) * 64 * 8192;

  int l15 = lane & 15, l4 = lane >> 4;
  int lofs = (l15 * 4 + l4) * 16;

  bf16x8 qf[8];
  {
    const U16* qp = Qb + (long)(s0 + w * 16 + l15) * 8192 + l4 * 8;
#pragma unroll
    for (int kc = 0; kc < 8; ++kc) qf[kc] = *(const bf16x8*)(qp + kc * 32);
  }
  asm volatile("s_waitcnt vmcnt(0)" ::: "memory");

  f32x4 acc[16] = {};
  float mrun = -1e30f, lrun = 0.0f;
  int qpos = s0 + w * 16 + l15;
  int qlo = s0 + w * 16, qhi = qlo + 15;

  int kstart = s0 - 1024; if (kstart < 0) kstart = 0;
  int kend = s0 + 64 + 1024; if (kend > 2048) kend = 2048;

  int sl15 = (t >> 2) & 15, sl4 = t & 3;
  int offK[4], offV[4];
#pragma unroll
  for (int i = 0; i < 4; ++i) {
    int f = i * 4 + w;
    offK[i] = ((f >> 3) * 16 + sl15) * 8192 + (f & 7) * 32 + sl4 * 8;
    offV[i] = (f * 16 + sl15) * 32 + sl4 * 8;
  }

  const U16* kb = Kb + (long)kstart * 8192;
  const U16* vt0 = VTb + (long)(kstart >> 5) * 8192;

  auto stage = [&](int buf) {
#pragma unroll
    for (int i = 0; i < 4; ++i)
      gload_lds16(kb + offK[i], (char*)&Ks[buf][0] + i * 4096 + w * 1024);
#pragma unroll
    for (int i = 0; i < 4; ++i)
      gload_lds16(vt0 + offV[i], (char*)&Vs[buf][0] + i * 4096 + w * 1024);
    kb += (long)32 * 8192;
    vt0 += 8192;
  };

  auto compute = [&](int buf, int k0) {
    f32x4 sAcc[2] = {};
    const char* Kc = (const char*)&Ks[buf][0] + lofs;
    __builtin_amdgcn_s_setprio(1);
#pragma unroll
    for (int kc = 0; kc < 8; ++kc) {
      bf16x8 a0 = *(const bf16x8*)(Kc + kc * 1024);
      bf16x8 a1 = *(const bf16x8*)(Kc + (8 + kc) * 1024);
      sAcc[0] = __builtin_amdgcn_mfma_f32_16x16x32_bf16(a0, qf[kc], sAcc[0], 0, 0, 0);
      sAcc[1] = __builtin_amdgcn_mfma_f32_16x16x32_bf16(a1, qf[kc], sAcc[1], 0, 0, 0);
    }
    __builtin_amdgcn_s_setprio(0);
    float sv[8];
#pragma unroll
    for (int mp = 0; mp < 2; ++mp)
#pragma unroll
      for (int jj = 0; jj < 4; ++jj) {
        float ex = __expf(sAcc[mp][jj] * 0.0025f);
        sv[mp * 4 + jj] = fmaf(-100.0f, __builtin_amdgcn_rcpf(ex + 1.0f), 50.0f);
      }
    bool full = ((qhi - k0) <= 1024) && ((k0 + 31 - qlo) <= 1024);
    if (!full) {
#pragma unroll
      for (int mp = 0; mp < 2; ++mp)
#pragma unroll
        for (int jj = 0; jj < 4; ++jj) {
          int key = k0 + mp * 16 + l4 * 4 + jj;
          int dd = qpos - key;
          if (dd < -1024 || dd > 1024) sv[mp * 4 + jj] = -3e38f;
        }
    }
    float tmax = sv[0];
#pragma unroll
    for (int i = 1; i < 8; ++i) tmax = fmaxf(tmax, sv[i]);
    tmax = fmaxf(tmax, __shfl_xor(tmax, 16));
    tmax = fmaxf(tmax, __shfl_xor(tmax, 32));
    bool skipall = __all((tmax <= mrun + 8.0f) ? 1 : 0) != 0;
    float mnew = skipall ? mrun : fmaxf(mrun, tmax);
    float pex[8];
    float psum = 0.0f;
#pragma unroll
    for (int i = 0; i < 8; ++i) { pex[i] = __expf(sv[i] - mnew); psum += pex[i]; }
    psum += __shfl_xor(psum, 16);
    psum += __shfl_xor(psum, 32);
    if (skipall) {
      lrun += psum;
    } else {
      float esc = __expf(mrun - mnew);
      f32x4 ev;
#pragma unroll
      for (int jj = 0; jj < 4; ++jj) ev[jj] = __shfl(esc, l4 * 4 + jj);
#pragma unroll
      for (int n = 0; n < 16; ++n) acc[n] *= ev;
      lrun = lrun * esc + psum;
      mrun = mnew;
    }
#pragma unroll
    for (int mp = 0; mp < 2; ++mp)
#pragma unroll
      for (int j2 = 0; j2 < 2; ++j2) {
        unsigned lo = f2bf(pex[mp * 4 + j2 * 2]);
        unsigned hi = f2bf(pex[mp * 4 + j2 * 2 + 1]);
        *(unsigned*)&Plds[w][l15 * 40 + mp * 16 + l4 * 4 + j2 * 2] = lo | (hi << 16);
      }
    asm volatile("s_waitcnt lgkmcnt(0)" ::: "memory");
    __builtin_amdgcn_sched_barrier(0);
    bf16x8 pa = *(const bf16x8*)&Plds[w][l15 * 40 + l4 * 8];
    const char* Vc = (const char*)&Vs[buf][0] + lofs;
    __builtin_amdgcn_s_setprio(1);
#pragma unroll
    for (int n = 0; n < 16; ++n) {
      bf16x8 vb = *(const bf16x8*)(Vc + n * 1024);
      acc[n] = __builtin_amdgcn_mfma_f32_16x16x32_bf16(pa, vb, acc[n], 0, 0, 0);
    }
    __builtin_amdgcn_s_setprio(0);
  };

  int cur = 0;
  stage(0);
  for (int k0 = kstart; k0 < kend - 32; k0 += 32) {
    stage(cur ^ 1);
    asm volatile("s_waitcnt vmcnt(8)" ::: "memory");
    __builtin_amdgcn_s_barrier();
    __builtin_amdgcn_sched_barrier(0);
    compute(cur, k0);
    __builtin_amdgcn_s_barrier();
    cur ^= 1;
  }
  asm volatile("s_waitcnt vmcnt(0)" ::: "memory");
  __builtin_amdgcn_s_barrier();
  __builtin_amdgcn_sched_barrier(0);
  compute(cur, kend - 32);

  f32x4 linv;
#pragma unroll
  for (int jj = 0; jj < 4; ++jj) linv[jj] = 1.0f / __shfl(lrun, l4 * 4 + jj);
#pragma unroll
  for (int jj = 0; jj < 4; ++jj) {
    int row = s0 + w * 16 + l4 * 4 + jj;
    U16* op = O + ((long)b * 2048 + row) * 4096 + h * 256 + l15;
#pragma unroll
    for (int n = 0; n < 16; ++n) op[n * 16] = f2bf(acc[n][jj] * linv[jj]);
  }
}

// ----------------------------------------------------------------------------
extern "C" void kernel_launch(void* const* d_in, const int* in_sizes, int n_in,
                              void* d_out, int out_size, void* d_ws, size_t ws_size,
                              hipStream_t stream) {
  if (n_in < 5) return;
  const float* hid = (const float*)d_in[0];
  const float* Wq  = (const float*)d_in[1];
  const float* Wk  = (const float*)d_in[2];
  const float* Wv  = (const float*)d_in[3];
  const float* Wo  = (const float*)d_in[4];

  char* ws = (char*)d_ws;
  size_t off = 0;
  auto alloc = [&](size_t bytes) {
    char* p = ws + off;
    off += (bytes + 255) & ~(size_t)255;
    return p;
  };
  float* cosT = (float*)alloc((size_t)2048 * 128 * 4);
  float* sinT = (float*)alloc((size_t)2048 * 128 * 4);
  U16*   Xb   = (U16*)alloc((size_t)4096 * 3584 * 2);   // reused: VT, then Wot
  U16*   Wt   = (U16*)alloc((size_t)8192 * 3584 * 2);   // reused: AttO
  U16*   QKV  = (U16*)alloc((size_t)4096 * 8192 * 2);
  if (off > ws_size) return;
  U16* VT   = Xb;
  U16* Wot  = Xb;
  U16* AttO = Wt;

  k_convert<<<7168, 256, 0, stream>>>(hid, Xb, (long)4096 * 3584);
  k_transpose<<<dim3(128, 112), 256, 0, stream>>>(Wq, Wt, 3584, 4096);
  k_transpose<<<dim3(64, 112), 256, 0, stream>>>(Wk, Wt + (size_t)4096 * 3584, 3584, 2048);
  k_transpose<<<dim3(64, 112), 256, 0, stream>>>(Wv, Wt + (size_t)6144 * 3584, 3584, 2048);
  k_rope_tables<<<1024, 256, 0, stream>>>(cosT, sinT);
  k_gemm8<0><<<dim3(32, 16), 512, 0, stream>>>(Xb, Wt, QKV, cosT, sinT, 4096, 8192, 3584);
  k_vtrans<<<dim3(64, 8, 16), 256, 0, stream>>>(QKV, VT);
  k_attn<<<dim3(32, 16, 2), 256, 0, stream>>>(QKV, VT, AttO);
  k_transpose<<<dim3(112, 128), 256, 0, stream>>>(Wo, Wot, 4096, 3584);
  k_gemm8<1><<<dim3(14, 16), 512, 0, stream>>>(AttO, Wot, d_out, cosT, sinT, 4096, 3584, 4096);
}